// Round 12
// baseline (154.589 us; speedup 1.0000x reference)
//
#include <hip/hip_runtime.h>
#include <math.h>

#define LQ 1024      // sequence length L
#define DM 512       // model dim D
#define HN 8         // heads
#define DHD 64       // head dim
#define ROWS 8192    // N*S*L
#define DE 128       // effective attention dim (2*DHD)
#define LOG2E 1.44269504088896f

typedef __attribute__((ext_vector_type(8))) short bf16x8;
typedef __attribute__((ext_vector_type(4))) float floatx4;
typedef unsigned short u16;

static __device__ __forceinline__ u16 f2bf(float x) {
    unsigned int u = __float_as_uint(x);
    u = (u + 0x7fffu + ((u >> 16) & 1u)) >> 16;   // round-nearest-even
    return (u16)u;
}

static __device__ __forceinline__ void gload16(const void* g, void* l) {
    __builtin_amdgcn_global_load_lds((const __attribute__((address_space(1))) void*)g,
                                     (__attribute__((address_space(3))) void*)l,
                                     16, 0, 0);
}

static __device__ __forceinline__ void cvt8(const float* s, u16* d, size_t o) {
    const float4* sp = (const float4*)s + 2 * o;
    float4 a = sp[0], b = sp[1];
    union { u16 u[8]; uint4 v; } ov;
    ov.u[0]=f2bf(a.x); ov.u[1]=f2bf(a.y); ov.u[2]=f2bf(a.z); ov.u[3]=f2bf(a.w);
    ov.u[4]=f2bf(b.x); ov.u[5]=f2bf(b.y); ov.u[6]=f2bf(b.z); ov.u[7]=f2bf(b.w);
    ((uint4*)d)[o] = ov.v;
}

// ---------------------------------------------------------------------------
// one fused cast dispatch: all weights + Q + K  (memory-bound)
// ---------------------------------------------------------------------------
__global__ __launch_bounds__(256)
void castall(const float* __restrict__ Wq, const float* __restrict__ Wk,
             const float* __restrict__ Wv, const float* __restrict__ We,
             const float* __restrict__ Wc, const float* __restrict__ Q,
             const float* __restrict__ K,
             u16* __restrict__ Wqb, u16* __restrict__ Wkvb,
             u16* __restrict__ Web, u16* __restrict__ Wcb,
             u16* __restrict__ Qb, u16* __restrict__ Kb)
{
    int i = blockIdx.x * 256 + threadIdx.x;      // vec8 id, total 1277952
    const float* s; u16* d; int o;
    if (i < 32768)        { s = Wq; d = Wqb;            o = i; }
    else if (i < 65536)   { s = Wk; d = Wkvb;           o = i - 32768; }
    else if (i < 98304)   { s = Wv; d = Wkvb + 262144;  o = i - 65536; }
    else if (i < 163840)  { s = We; d = Web;            o = i - 98304; }
    else if (i < 229376)  { s = Wc; d = Wcb;            o = i - 163840; }
    else if (i < 753664)  { s = Q;  d = Qb;             o = i - 229376; }
    else                  { s = K;  d = Kb;             o = i - 753664; }
    cvt8(s, d, (size_t)o);
}

// ---------------------------------------------------------------------------
// Fused projection GEMM: one dispatch, grid (64, 12).
// blockIdx.y < 4 : Q-proj -> A (sin/cos, log2e folded)
// blockIdx.y >= 4: KV-proj -> B (n0<512) / Vt (n0>=512, per-head transposed)
// 128x128 tile, BK=64, counted-vmcnt dual-barrier 2-phase dbuf,
// pure global_load_lds staging w/ XOR swizzle. Kd = 512 for both paths.
// ---------------------------------------------------------------------------
__global__ __launch_bounds__(256)
void proj_qkv(const u16* __restrict__ Qb, const u16* __restrict__ Kb,
              const u16* __restrict__ Wqb, const u16* __restrict__ Wkvb,
              const float* __restrict__ bq, const float* __restrict__ bk,
              const float* __restrict__ bv,
              u16* __restrict__ Abf, u16* __restrict__ Bbf, u16* __restrict__ Vtb,
              const float* __restrict__ Pq, const float* __restrict__ Pk,
              const float* __restrict__ Wp, const float* __restrict__ bp)
{
    const bool isQ = blockIdx.y < 4;
    const int m0 = blockIdx.x * 128;
    const int n0 = (isQ ? blockIdx.y : blockIdx.y - 4) * 128;
    const u16* Xb = isQ ? Qb : Kb;
    const u16* W  = isQ ? Wqb : Wkvb;
    const float* Pph = isQ ? Pq : Pk;
    const int Kd = DM;

    const int tid = threadIdx.x;
    const int w = tid >> 6, lane = tid & 63;
    const int lr = lane & 15, lg = lane >> 4;
    const int wm = w >> 1, wn = w & 1;

    __shared__ __align__(16) u16 AsL[2][128 * 64];
    __shared__ __align__(16) u16 BsL[2][128 * 64];

    floatx4 acc[4][4] = {};
    const int xorp = (lr & 7) << 4;
    const int colb = lg << 4;

    auto stage = [&](int t, int b) {
        const size_t ko = (size_t)t * 64;
        #pragma unroll
        for (int r = 0; r < 4; ++r) {
            const int cid = r * 256 + tid;
            const int row = cid >> 3, c16 = cid & 7;
            const int kc = ((c16 ^ (row & 7)) << 3);
            gload16(&Xb[(size_t)(m0 + row) * Kd + ko + kc], &AsL[b][cid * 8]);
        }
        #pragma unroll
        for (int r = 0; r < 4; ++r) {
            const int cid = r * 256 + tid;
            const int row = cid >> 3, c16 = cid & 7;
            const int kc = ((c16 ^ (row & 7)) << 3);
            gload16(&W[(size_t)(n0 + row) * Kd + ko + kc], &BsL[b][cid * 8]);
        }
    };

    const int nt = Kd >> 6;
    stage(0, 0);
    int c = 0;
    for (int t = 0; t < nt; ++t) {
        if (t + 1 < nt) {
            stage(t + 1, c ^ 1);                       // 8 loads stay in flight
            asm volatile("s_waitcnt vmcnt(8)" ::: "memory");
        } else {
            asm volatile("s_waitcnt vmcnt(0)" ::: "memory");
        }
        __builtin_amdgcn_sched_barrier(0);
        __builtin_amdgcn_s_barrier();                  // buf c staged for all waves

        const char* la = (const char*)AsL[c];
        const char* lb = (const char*)BsL[c];
        __builtin_amdgcn_s_setprio(1);
        #pragma unroll
        for (int ks = 0; ks < 2; ++ks) {
            const int cb = (ks * 64 + colb) ^ xorp;
            bf16x8 a[4], b[4];
            #pragma unroll
            for (int i = 0; i < 4; ++i)
                a[i] = *(const bf16x8*)(la + (((wm * 64 + i * 16 + lr) << 7) + cb));
            #pragma unroll
            for (int j = 0; j < 4; ++j)
                b[j] = *(const bf16x8*)(lb + (((wn * 64 + j * 16 + lr) << 7) + cb));
            #pragma unroll
            for (int i = 0; i < 4; ++i)
                #pragma unroll
                for (int j = 0; j < 4; ++j)
                    acc[i][j] = __builtin_amdgcn_mfma_f32_16x16x32_bf16(a[i], b[j], acc[i][j], 0, 0, 0);
        }
        __builtin_amdgcn_s_setprio(0);
        __builtin_amdgcn_s_barrier();                  // all waves done reading buf c
        __builtin_amdgcn_sched_barrier(0);
        c ^= 1;
    }

    if (isQ) {          // -> A with phases (log2e folded)
        #pragma unroll
        for (int j = 0; j < 4; ++j) {
            const int col = n0 + wn * 64 + j * 16 + lr;
            const float w0 = Wp[col * 3], w1 = Wp[col * 3 + 1], w2 = Wp[col * 3 + 2];
            const float bpd = bp[col], bi = bq[col];
            const int hh = col >> 6, dh = col & 63;
            #pragma unroll
            for (int i = 0; i < 4; ++i)
                #pragma unroll
                for (int rr = 0; rr < 4; ++rr) {
                    const int row = m0 + wm * 64 + i * 16 + lg * 4 + rr;
                    const int ns = row >> 10, l = row & 1023;
                    const float p = Pph[row * 3] * w0 + Pph[row * 3 + 1] * w1
                                  + Pph[row * 3 + 2] * w2 + bpd;
                    float sn, cs;
                    __sincosf(p, &sn, &cs);
                    const float v = acc[i][j][rr] + bi;
                    const size_t e = (((size_t)(ns * HN + hh)) * LQ + l) * DE + dh;
                    Abf[e]      = f2bf(v * sn * LOG2E);
                    Abf[e + 64] = f2bf(-v * cs * LOG2E);
                }
        }
    } else if (n0 < 512) {    // K half -> B with phases
        #pragma unroll
        for (int j = 0; j < 4; ++j) {
            const int col = n0 + wn * 64 + j * 16 + lr;
            const float w0 = Wp[col * 3], w1 = Wp[col * 3 + 1], w2 = Wp[col * 3 + 2];
            const float bi = bk[col];
            const int hh = col >> 6, dh = col & 63;
            #pragma unroll
            for (int i = 0; i < 4; ++i)
                #pragma unroll
                for (int rr = 0; rr < 4; ++rr) {
                    const int row = m0 + wm * 64 + i * 16 + lg * 4 + rr;
                    const int ns = row >> 10, l = row & 1023;
                    const float p = Pph[row * 3] * w0 + Pph[row * 3 + 1] * w1
                                  + Pph[row * 3 + 2] * w2;      // pk - b
                    float sn, cs;
                    __sincosf(p, &sn, &cs);
                    const float v = acc[i][j][rr] + bi;
                    const size_t e = (((size_t)(ns * HN + hh)) * LQ + l) * DE + dh;
                    Bbf[e]      = f2bf(v * cs);
                    Bbf[e + 64] = f2bf(v * sn);
                }
        }
    } else {                  // V half -> Vt (per-head transposed)
        #pragma unroll
        for (int j = 0; j < 4; ++j) {
            const int col = n0 + wn * 64 + j * 16 + lr;
            const int c2 = col - 512;
            const float bi = bv[c2];
            const int hh = c2 >> 6, dh = c2 & 63;
            #pragma unroll
            for (int i = 0; i < 4; ++i)
                #pragma unroll
                for (int rr = 0; rr < 4; ++rr) {
                    const int row = m0 + wm * 64 + i * 16 + lg * 4 + rr;
                    const int ns = row >> 10, l = row & 1023;
                    const float v = acc[i][j][rr] + bi;
                    Vtb[((size_t)((ns * HN + hh) * DHD + dh)) * LQ + l] = f2bf(v);
                }
        }
    }
}

// ---------------------------------------------------------------------------
// FFN GEMM: 128x128, BK=64, counted-vmcnt dual-barrier 2-phase dbuf.
// MODE 0: f32 out + bias + BN partials   MODE 1: bf16 out + bias + relu
// ---------------------------------------------------------------------------
template<int MODE>
__global__ __launch_bounds__(256)
void gemm_k(const u16* __restrict__ Xb, const u16* __restrict__ W,
            const float* __restrict__ bias, void* __restrict__ out,
            int Kd, int Nn, float* __restrict__ bnp)
{
    const int m0 = blockIdx.x * 128, n0 = blockIdx.y * 128;
    const int tid = threadIdx.x;
    const int w = tid >> 6, lane = tid & 63;
    const int lr = lane & 15, lg = lane >> 4;
    const int wm = w >> 1, wn = w & 1;

    __shared__ __align__(16) u16 AsL[2][128 * 64];
    __shared__ __align__(16) u16 BsL[2][128 * 64];
    __shared__ float BnL[2][2][4][16][2];

    floatx4 acc[4][4] = {};
    const int xorp = (lr & 7) << 4;
    const int colb = lg << 4;

    auto stage = [&](int t, int b) {
        const size_t ko = (size_t)t * 64;
        #pragma unroll
        for (int r = 0; r < 4; ++r) {
            const int cid = r * 256 + tid;
            const int row = cid >> 3, c16 = cid & 7;
            const int kc = ((c16 ^ (row & 7)) << 3);
            gload16(&Xb[(size_t)(m0 + row) * Kd + ko + kc], &AsL[b][cid * 8]);
        }
        #pragma unroll
        for (int r = 0; r < 4; ++r) {
            const int cid = r * 256 + tid;
            const int row = cid >> 3, c16 = cid & 7;
            const int kc = ((c16 ^ (row & 7)) << 3);
            gload16(&W[(size_t)(n0 + row) * Kd + ko + kc], &BsL[b][cid * 8]);
        }
    };

    const int nt = Kd >> 6;
    stage(0, 0);
    int c = 0;
    for (int t = 0; t < nt; ++t) {
        if (t + 1 < nt) {
            stage(t + 1, c ^ 1);                       // 8 loads stay in flight
            asm volatile("s_waitcnt vmcnt(8)" ::: "memory");
        } else {
            asm volatile("s_waitcnt vmcnt(0)" ::: "memory");
        }
        __builtin_amdgcn_sched_barrier(0);
        __builtin_amdgcn_s_barrier();                  // buf c staged for all waves

        const char* la = (const char*)AsL[c];
        const char* lb = (const char*)BsL[c];
        __builtin_amdgcn_s_setprio(1);
        #pragma unroll
        for (int ks = 0; ks < 2; ++ks) {
            const int cb = (ks * 64 + colb) ^ xorp;
            bf16x8 a[4], b[4];
            #pragma unroll
            for (int i = 0; i < 4; ++i)
                a[i] = *(const bf16x8*)(la + (((wm * 64 + i * 16 + lr) << 7) + cb));
            #pragma unroll
            for (int j = 0; j < 4; ++j)
                b[j] = *(const bf16x8*)(lb + (((wn * 64 + j * 16 + lr) << 7) + cb));
            #pragma unroll
            for (int i = 0; i < 4; ++i)
                #pragma unroll
                for (int j = 0; j < 4; ++j)
                    acc[i][j] = __builtin_amdgcn_mfma_f32_16x16x32_bf16(a[i], b[j], acc[i][j], 0, 0, 0);
        }
        __builtin_amdgcn_s_setprio(0);
        __builtin_amdgcn_s_barrier();                  // all waves done reading buf c
        __builtin_amdgcn_sched_barrier(0);
        c ^= 1;
    }

    float bs[4], bs2[4];
    #pragma unroll
    for (int j = 0; j < 4; ++j) { bs[j] = 0.f; bs2[j] = 0.f; }
    #pragma unroll
    for (int j = 0; j < 4; ++j) {
        const int col = n0 + wn * 64 + j * 16 + lr;
        const float bi = bias[col];
        #pragma unroll
        for (int i = 0; i < 4; ++i)
            #pragma unroll
            for (int rr = 0; rr < 4; ++rr) {
                const int row = m0 + wm * 64 + i * 16 + lg * 4 + rr;
                float v = acc[i][j][rr] + bi;
                if (MODE == 1) {
                    v = fmaxf(v, 0.f);
                    ((u16*)out)[(size_t)row * Nn + col] = f2bf(v);
                } else {
                    ((float*)out)[(size_t)row * Nn + col] = v;
                    bs[j] += v; bs2[j] += v * v;
                }
            }
    }
    if (MODE == 0) {    // BN partial over this m-tile's 128 rows
        #pragma unroll
        for (int j = 0; j < 4; ++j) {
            float s = bs[j], s2 = bs2[j];
            s  += __shfl_xor(s, 16);  s  += __shfl_xor(s, 32);
            s2 += __shfl_xor(s2, 16); s2 += __shfl_xor(s2, 32);
            if (lg == 0) { BnL[wm][wn][j][lr][0] = s; BnL[wm][wn][j][lr][1] = s2; }
        }
        __syncthreads();
        if (tid < 128) {
            const int wn2 = tid >> 6, j2 = (tid >> 4) & 3, lr2 = tid & 15;
            const float s  = BnL[0][wn2][j2][lr2][0] + BnL[1][wn2][j2][lr2][0];
            const float s2 = BnL[0][wn2][j2][lr2][1] + BnL[1][wn2][j2][lr2][1];
            const int col = n0 + tid;
            bnp[(size_t)blockIdx.x * 512 + col]         = s;
            bnp[32768 + (size_t)blockIdx.x * 512 + col] = s2;
        }
    }
}

// ---------------------------------------------------------------------------
// Flash attention: 512-thr blocks (8 waves), QBLK=256, KVBLK=64, dual 16-q
// groups per wave. K double-buffered, V SINGLE-buffered (issued at tile top,
// waited after QK via a third barrier) -> LDS 76 KB -> 2 blocks/CU =
// 4 waves/SIMD. No-max softmax; counted-vmcnt.
// vmcnt discipline (per-thread issue order per iter: V(kt), K(kt+1)a,b):
//   barrier#1  : K(kt) done   -> vmcnt(3)  (tail: 1)
//   barrier#1.5: V(kt) done   -> vmcnt(2)  (tail: 0)
// ---------------------------------------------------------------------------
__global__ __launch_bounds__(512, 4)
void attn_mfma(const u16* __restrict__ Ag, const u16* __restrict__ Bg,
               const u16* __restrict__ Vtg, u16* __restrict__ Tbf)
{
    int bid = blockIdx.x;
    bid = (bid & 7) * 32 + (bid >> 3);    // XCD swizzle (256 % 8 == 0): 8 heads/XCD
    const int head = bid >> 2;            // 0..63
    const int row0 = (bid & 3) * 256;
    const int ns = head >> 3, h = head & 7;
    const int tid = threadIdx.x, w = tid >> 6, lane = tid & 63;
    const int lr = lane & 15, lg = lane >> 4;

    __shared__ __align__(16) u16 BsL[2][64 * 128];   // 32 KB (K, dbuf)
    __shared__ __align__(16) u16 VtL[64 * 64];       //  8 KB (V, single)
    __shared__ __align__(16) u16 Ps[8][32][72];      // 36 KB

    // Q fragments -> registers: group A rows w*32+lr, group B rows w*32+16+lr
    bf16x8 qfA[4], qfB[4];
    {
        const size_t rb = ((size_t)head * LQ + row0 + w * 32 + lr) * DE;
        #pragma unroll
        for (int ks = 0; ks < 4; ++ks) {
            qfA[ks] = *(const bf16x8*)&Ag[rb + ks * 32 + lg * 8];
            qfB[ks] = *(const bf16x8*)&Ag[rb + 16 * DE + ks * 32 + lg * 8];
        }
    }

    auto stageK = [&](int kt, int b) {                // 2 gloads / thread
        #pragma unroll
        for (int r = 0; r < 2; ++r) {
            const int cid = r * 512 + tid;
            const int row = cid >> 4, c16 = cid & 15;
            const int kc = ((c16 ^ (row & 7)) << 3);
            gload16(&Bg[((size_t)head * LQ + kt * 64 + row) * DE + kc], &BsL[b][cid * 8]);
        }
    };
    auto stageV = [&](int kt) {                       // 1 gload / thread
        const int row = tid >> 3, c16 = tid & 7;
        const int kc = ((c16 ^ (row & 7)) << 3);
        gload16(&Vtg[((size_t)head * DHD + row) * LQ + kt * 64 + kc], &VtL[tid * 8]);
    };

    stageK(0, 0);
    stageV(0);

    floatx4 oA[4] = {}, oB[4] = {};
    float lsA = 0.f, lsB = 0.f;
    const int xorp = (lr & 7) << 4;
    const int colb = lg << 4;
    int c = 0;

    for (int kt = 0; kt < 16; ++kt) {
        if (kt > 0) stageV(kt);                        // after barrier#2 of kt-1
        if (kt < 15) {
            stageK(kt + 1, c ^ 1);
            asm volatile("s_waitcnt vmcnt(3)" ::: "memory");   // K(kt) done
        } else {
            asm volatile("s_waitcnt vmcnt(1)" ::: "memory");
        }
        __builtin_amdgcn_sched_barrier(0);
        __builtin_amdgcn_s_barrier();                 // barrier#1: K[c] staged

        const char* lb = (const char*)BsL[c];
        const char* lv = (const char*)VtL;

        // ---- S^T strips, kfrag shared across both q-groups ----
        floatx4 sA[4] = {}, sB[4] = {};
        __builtin_amdgcn_s_setprio(1);
        #pragma unroll
        for (int ks = 0; ks < 4; ++ks) {
            const int cb = (ks * 64 + colb) ^ xorp;
            bf16x8 kf[4];
            #pragma unroll
            for (int j = 0; j < 4; ++j)
                kf[j] = *(const bf16x8*)(lb + (((j * 16 + lr) << 8) + cb));
            #pragma unroll
            for (int j = 0; j < 4; ++j) {
                sA[j] = __builtin_amdgcn_mfma_f32_16x16x32_bf16(kf[j], qfA[ks], sA[j], 0, 0, 0);
                sB[j] = __builtin_amdgcn_mfma_f32_16x16x32_bf16(kf[j], qfB[ks], sB[j], 0, 0, 0);
            }
        }
        __builtin_amdgcn_s_setprio(0);

        // ---- no-max softmax ----
        float tsa = 0.f, tsb = 0.f;
        #pragma unroll
        for (int j = 0; j < 4; ++j)
            #pragma unroll
            for (int r = 0; r < 4; ++r) {
                float ea = exp2f(sA[j][r]); sA[j][r] = ea; tsa += ea;
                float eb = exp2f(sB[j][r]); sB[j][r] = eb; tsb += eb;
            }
        lsA += tsa; lsB += tsb;

        // ---- P -> per-wave LDS (cvt_pk), rows 0-15 = A, 16-31 = B ----
        #pragma unroll
        for (int j = 0; j < 4; ++j) {
            unsigned plo, phi;
            asm("v_cvt_pk_bf16_f32 %0, %1, %2" : "=v"(plo) : "v"(sA[j][0]), "v"(sA[j][1]));
            asm("v_cvt_pk_bf16_f32 %0, %1, %2" : "=v"(phi) : "v"(sA[j][2]), "v"(sA[j][3]));
            uint2 pv; pv.x = plo; pv.y = phi;
            *(uint2*)&Ps[w][lr][j * 16 + lg * 4] = pv;
            asm("v_cvt_pk_bf16_f32 %0, %1, %2" : "=v"(plo) : "v"(sB[j][0]), "v"(sB[j][1]));
            asm("v_cvt_pk_bf16_f32 %0, %1, %2" : "=v"(phi) : "v"(sB[j][2]), "v"(sB[j][3]));
            pv.x = plo; pv.y = phi;
            *(uint2*)&Ps[w][16 + lr][j * 16 + lg * 4] = pv;
        }

        // ---- wait V(kt) landed for ALL waves (covered by QK phase) ----
        if (kt < 15) asm volatile("s_waitcnt vmcnt(2)" ::: "memory");
        else         asm volatile("s_waitcnt vmcnt(0)" ::: "memory");
        __builtin_amdgcn_sched_barrier(0);
        __builtin_amdgcn_s_barrier();                 // barrier#1.5: V staged

        // ---- PV: vfrag shared across both q-groups ----
        __builtin_amdgcn_s_setprio(1);
        #pragma unroll
        for (int ks2 = 0; ks2 < 2; ++ks2) {
            const int cb = (ks2 * 64 + colb) ^ xorp;
            bf16x8 pfA = *(const bf16x8*)&Ps[w][lr][ks2 * 32 + lg * 8];
            bf16x8 pfB = *(const bf16x8*)&Ps[w][16 + lr][ks2 * 32 + lg * 8];
            #pragma unroll
            for (int m = 0; m < 4; ++m) {
                bf16x8 vf = *(const bf16x8*)(lv + (((m * 16 + lr) << 7) + cb));
                oA[m] = __builtin_amdgcn_mfma_f32_16x16x32_bf16(vf, pfA, oA[m], 0, 0, 0);
                oB[m] = __builtin_amdgcn_mfma_f32_16x16x32_bf16(vf, pfB, oB[m], 0, 0, 0);
            }
        }
        __builtin_amdgcn_s_setprio(0);
        __builtin_amdgcn_s_barrier();                 // barrier#2: done with V(kt), K[c]
        __builtin_amdgcn_sched_barrier(0);
        c ^= 1;
    }

    // denominators (once), normalize, write merged-head T (bf16)
    lsA += __shfl_xor(lsA, 16); lsA += __shfl_xor(lsA, 32);
    lsB += __shfl_xor(lsB, 16); lsB += __shfl_xor(lsB, 32);
    const float invA = 1.f / lsA, invB = 1.f / lsB;
    const size_t trA = ((size_t)ns * LQ + row0 + w * 32 + lr) * DM + h * DHD;
    const size_t trB = trA + (size_t)16 * DM;
    #pragma unroll
    for (int m = 0; m < 4; ++m) {
        union { u16 u[4]; uint2 v; } pk;
        pk.u[0] = f2bf(oA[m][0] * invA); pk.u[1] = f2bf(oA[m][1] * invA);
        pk.u[2] = f2bf(oA[m][2] * invA); pk.u[3] = f2bf(oA[m][3] * invA);
        *(uint2*)&Tbf[trA + m * 16 + lg * 4] = pk.v;
        pk.u[0] = f2bf(oB[m][0] * invB); pk.u[1] = f2bf(oB[m][1] * invB);
        pk.u[2] = f2bf(oB[m][2] * invB); pk.u[3] = f2bf(oB[m][3] * invB);
        *(uint2*)&Tbf[trB + m * 16 + lg * 4] = pk.v;
    }
}

// ---------------------------------------------------------------------------
// BN: reduce per-block partials (64 m-blocks) -> stats; then final (float4)
// ---------------------------------------------------------------------------
__global__ __launch_bounds__(256)
void bn_reduce(const float* __restrict__ part, float* __restrict__ stats)
{
    const int cx = blockIdx.x * 256 + threadIdx.x;   // 0..511
    float s = 0.f, s2 = 0.f;
    for (int b = 0; b < 64; ++b) {
        s  += part[(size_t)b * 512 + cx];
        s2 += part[32768 + (size_t)b * 512 + cx];
    }
    stats[cx] = s;
    stats[512 + cx] = s2;
}

__global__ __launch_bounds__(256)
void bn_final(const float* __restrict__ Y, const float* __restrict__ Qin,
              const float* __restrict__ stats,
              const float* __restrict__ gamma, const float* __restrict__ beta,
              float* __restrict__ out)
{
    const int i4 = blockIdx.x * 256 + threadIdx.x;   // 0..ROWS*DM/4-1
    const int c4 = (i4 & 127) * 4;                   // channel base
    const float4 sm  = *(const float4*)&stats[c4];
    const float4 sq  = *(const float4*)&stats[512 + c4];
    const float4 gm  = *(const float4*)&gamma[c4];
    const float4 bt  = *(const float4*)&beta[c4];
    const float4 y   = *(const float4*)&Y[(size_t)i4 * 4];
    const float4 q   = *(const float4*)&Qin[(size_t)i4 * 4];
    float4 o;
    {
        const float mu = sm.x * (1.f / ROWS);
        const float rs = rsqrtf(sq.x * (1.f / ROWS) - mu * mu + 1e-5f);
        o.x = q.x + (y.x - mu) * rs * gm.x + bt.x;
    }
    {
        const float mu = sm.y * (1.f / ROWS);
        const float rs = rsqrtf(sq.y * (1.f / ROWS) - mu * mu + 1e-5f);
        o.y = q.y + (y.y - mu) * rs * gm.y + bt.y;
    }
    {
        const float mu = sm.z * (1.f / ROWS);
        const float rs = rsqrtf(sq.z * (1.f / ROWS) - mu * mu + 1e-5f);
        o.z = q.z + (y.z - mu) * rs * gm.z + bt.z;
    }
    {
        const float mu = sm.w * (1.f / ROWS);
        const float rs = rsqrtf(sq.w * (1.f / ROWS) - mu * mu + 1e-5f);
        o.w = q.w + (y.w - mu) * rs * gm.w + bt.w;
    }
    *(float4*)&out[(size_t)i4 * 4] = o;
}

// ---------------------------------------------------------------------------
extern "C" void kernel_launch(void* const* d_in, const int* in_sizes, int n_in,
                              void* d_out, int out_size, void* d_ws, size_t ws_size,
                              hipStream_t stream)
{
    (void)in_sizes; (void)n_in; (void)out_size; (void)ws_size;

    const float* Q    = (const float*)d_in[0];
    const float* K    = (const float*)d_in[1];
    const float* Pq   = (const float*)d_in[2];
    const float* Pk   = (const float*)d_in[3];
    const float* Wq   = (const float*)d_in[4];
    const float* bq   = (const float*)d_in[5];
    const float* Wk   = (const float*)d_in[6];
    const float* bk   = (const float*)d_in[7];
    const float* Wv   = (const float*)d_in[8];
    const float* bv   = (const float*)d_in[9];
    const float* Wp   = (const float*)d_in[10];
    const float* bp   = (const float*)d_in[11];
    const float* We   = (const float*)d_in[12];
    const float* be   = (const float*)d_in[13];
    const float* Wc   = (const float*)d_in[14];
    const float* bc   = (const float*)d_in[15];
    const float* gamma= (const float*)d_in[16];
    const float* beta = (const float*)d_in[17];

    const size_t MB = 1u << 20;
    char* w8 = (char*)d_ws;
    u16*  Abf  = (u16*)(w8);                  // 16 MB (A operands)
    u16*  Bbf  = (u16*)(w8 + 16 * MB);        // 16 MB
    u16*  Vtb  = (u16*)(w8 + 32 * MB);        //  8 MB
    u16*  Tbf  = (u16*)(w8 + 40 * MB);        //  8 MB
    u16*  H1b  = (u16*)(w8 + 48 * MB);        // 16 MB
    u16*  Qbf  = (u16*)(w8 + 64 * MB);        //  8 MB
    u16*  Kbf  = (u16*)(w8 + 72 * MB);        //  8 MB
    float* Y   = (float*)(w8);                // 16 MB (reuses Abf after attn)
    float* part  = (float*)(w8 + 16 * MB);    // 256 KB (reuses Bbf after attn)
    float* stats = (float*)(w8 + 17 * MB);    //  4 KB
    u16*  Wqb  = (u16*)(w8 + 80 * MB);                    // 0.5 MB
    u16*  Wkvb = (u16*)(w8 + 80 * MB + 512 * 1024);       // 1 MB
    u16*  Web  = (u16*)(w8 + 80 * MB + 1536 * 1024);      // 1 MB
    u16*  Wcb  = (u16*)(w8 + 80 * MB + 2560 * 1024);      // 1 MB

    dim3 blk256(256);

    // one fused cast: weights + Q + K
    castall<<<4992, blk256, 0, stream>>>(Wq, Wk, Wv, We, Wc, Q, K,
                                         Wqb, Wkvb, Web, Wcb, Qbf, Kbf);

    // fused Q-proj + KV-proj (one dispatch, 768 blocks, pure gload_lds path)
    proj_qkv<<<dim3(64, 12), blk256, 0, stream>>>(Qbf, Kbf, Wqb, Wkvb,
        bq, bk, bv, Abf, Bbf, Vtb, Pq, Pk, Wp, bp);

    // flash attention (256 blocks x 8 waves, dual-group, 2 blocks/CU)
    attn_mfma<<<256, dim3(512), 0, stream>>>(Abf, Bbf, Vtb, Tbf);

    // FFN
    gemm_k<1><<<dim3(64, 8), blk256, 0, stream>>>(Tbf, Web, be, H1b, DM, 2 * DM, nullptr);
    gemm_k<0><<<dim3(64, 4), blk256, 0, stream>>>(H1b, Wcb, bc, Y, 2 * DM, DM, part);

    // BN stats + final
    bn_reduce<<<2, blk256, 0, stream>>>(part, stats);
    bn_final<<<ROWS * DM / 1024, blk256, 0, stream>>>(Y, Q, stats, gamma, beta,
                                                      (float*)d_out);
}

// Round 13
// 141.164 us; speedup vs baseline: 1.0951x; 1.0951x over previous
//
#include <hip/hip_runtime.h>
#include <math.h>

#define LQ 1024      // sequence length L
#define DM 512       // model dim D
#define HN 8         // heads
#define DHD 64       // head dim
#define ROWS 8192    // N*S*L
#define DE 128       // effective attention dim (2*DHD)
#define LOG2E 1.44269504088896f

typedef __attribute__((ext_vector_type(8))) short bf16x8;
typedef __attribute__((ext_vector_type(4))) float floatx4;
typedef unsigned short u16;

static __device__ __forceinline__ u16 f2bf(float x) {
    unsigned int u = __float_as_uint(x);
    u = (u + 0x7fffu + ((u >> 16) & 1u)) >> 16;   // round-nearest-even
    return (u16)u;
}

static __device__ __forceinline__ float bf2f(u16 u) {
    return __uint_as_float(((unsigned)u) << 16);
}

static __device__ __forceinline__ void gload16(const void* g, void* l) {
    __builtin_amdgcn_global_load_lds((const __attribute__((address_space(1))) void*)g,
                                     (__attribute__((address_space(3))) void*)l,
                                     16, 0, 0);
}

static __device__ __forceinline__ void cvt8(const float* s, u16* d, size_t o) {
    const float4* sp = (const float4*)s + 2 * o;
    float4 a = sp[0], b = sp[1];
    union { u16 u[8]; uint4 v; } ov;
    ov.u[0]=f2bf(a.x); ov.u[1]=f2bf(a.y); ov.u[2]=f2bf(a.z); ov.u[3]=f2bf(a.w);
    ov.u[4]=f2bf(b.x); ov.u[5]=f2bf(b.y); ov.u[6]=f2bf(b.z); ov.u[7]=f2bf(b.w);
    ((uint4*)d)[o] = ov.v;
}

// ---------------------------------------------------------------------------
// one fused cast dispatch: all weights + Q + K  (memory-bound)
// ---------------------------------------------------------------------------
__global__ __launch_bounds__(256)
void castall(const float* __restrict__ Wq, const float* __restrict__ Wk,
             const float* __restrict__ Wv, const float* __restrict__ We,
             const float* __restrict__ Wc, const float* __restrict__ Q,
             const float* __restrict__ K,
             u16* __restrict__ Wqb, u16* __restrict__ Wkvb,
             u16* __restrict__ Web, u16* __restrict__ Wcb,
             u16* __restrict__ Qb, u16* __restrict__ Kb)
{
    int i = blockIdx.x * 256 + threadIdx.x;      // vec8 id, total 1277952
    const float* s; u16* d; int o;
    if (i < 32768)        { s = Wq; d = Wqb;            o = i; }
    else if (i < 65536)   { s = Wk; d = Wkvb;           o = i - 32768; }
    else if (i < 98304)   { s = Wv; d = Wkvb + 262144;  o = i - 65536; }
    else if (i < 163840)  { s = We; d = Web;            o = i - 98304; }
    else if (i < 229376)  { s = Wc; d = Wcb;            o = i - 163840; }
    else if (i < 753664)  { s = Q;  d = Qb;             o = i - 229376; }
    else                  { s = K;  d = Kb;             o = i - 753664; }
    cvt8(s, d, (size_t)o);
}

// ---------------------------------------------------------------------------
// Fused projection GEMM: one dispatch, grid (64, 12).
// blockIdx.y < 4 : Q-proj -> A (sin/cos, log2e folded)
// blockIdx.y >= 4: KV-proj -> B (n0<512) / Vt (n0>=512, per-head transposed)
// 128x128 tile, BK=64, counted-vmcnt dual-barrier 2-phase dbuf,
// pure global_load_lds staging w/ XOR swizzle. Kd = 512 for both paths.
// ---------------------------------------------------------------------------
__global__ __launch_bounds__(256)
void proj_qkv(const u16* __restrict__ Qb, const u16* __restrict__ Kb,
              const u16* __restrict__ Wqb, const u16* __restrict__ Wkvb,
              const float* __restrict__ bq, const float* __restrict__ bk,
              const float* __restrict__ bv,
              u16* __restrict__ Abf, u16* __restrict__ Bbf, u16* __restrict__ Vtb,
              const float* __restrict__ Pq, const float* __restrict__ Pk,
              const float* __restrict__ Wp, const float* __restrict__ bp)
{
    const bool isQ = blockIdx.y < 4;
    const int m0 = blockIdx.x * 128;
    const int n0 = (isQ ? blockIdx.y : blockIdx.y - 4) * 128;
    const u16* Xb = isQ ? Qb : Kb;
    const u16* W  = isQ ? Wqb : Wkvb;
    const float* Pph = isQ ? Pq : Pk;
    const int Kd = DM;

    const int tid = threadIdx.x;
    const int w = tid >> 6, lane = tid & 63;
    const int lr = lane & 15, lg = lane >> 4;
    const int wm = w >> 1, wn = w & 1;

    __shared__ __align__(16) u16 AsL[2][128 * 64];
    __shared__ __align__(16) u16 BsL[2][128 * 64];

    floatx4 acc[4][4] = {};
    const int xorp = (lr & 7) << 4;
    const int colb = lg << 4;

    auto stage = [&](int t, int b) {
        const size_t ko = (size_t)t * 64;
        #pragma unroll
        for (int r = 0; r < 4; ++r) {
            const int cid = r * 256 + tid;
            const int row = cid >> 3, c16 = cid & 7;
            const int kc = ((c16 ^ (row & 7)) << 3);
            gload16(&Xb[(size_t)(m0 + row) * Kd + ko + kc], &AsL[b][cid * 8]);
        }
        #pragma unroll
        for (int r = 0; r < 4; ++r) {
            const int cid = r * 256 + tid;
            const int row = cid >> 3, c16 = cid & 7;
            const int kc = ((c16 ^ (row & 7)) << 3);
            gload16(&W[(size_t)(n0 + row) * Kd + ko + kc], &BsL[b][cid * 8]);
        }
    };

    const int nt = Kd >> 6;
    stage(0, 0);
    int c = 0;
    for (int t = 0; t < nt; ++t) {
        if (t + 1 < nt) {
            stage(t + 1, c ^ 1);                       // 8 loads stay in flight
            asm volatile("s_waitcnt vmcnt(8)" ::: "memory");
        } else {
            asm volatile("s_waitcnt vmcnt(0)" ::: "memory");
        }
        __builtin_amdgcn_sched_barrier(0);
        __builtin_amdgcn_s_barrier();                  // buf c staged for all waves

        const char* la = (const char*)AsL[c];
        const char* lb = (const char*)BsL[c];
        __builtin_amdgcn_s_setprio(1);
        #pragma unroll
        for (int ks = 0; ks < 2; ++ks) {
            const int cb = (ks * 64 + colb) ^ xorp;
            bf16x8 a[4], b[4];
            #pragma unroll
            for (int i = 0; i < 4; ++i)
                a[i] = *(const bf16x8*)(la + (((wm * 64 + i * 16 + lr) << 7) + cb));
            #pragma unroll
            for (int j = 0; j < 4; ++j)
                b[j] = *(const bf16x8*)(lb + (((wn * 64 + j * 16 + lr) << 7) + cb));
            #pragma unroll
            for (int i = 0; i < 4; ++i)
                #pragma unroll
                for (int j = 0; j < 4; ++j)
                    acc[i][j] = __builtin_amdgcn_mfma_f32_16x16x32_bf16(a[i], b[j], acc[i][j], 0, 0, 0);
        }
        __builtin_amdgcn_s_setprio(0);
        __builtin_amdgcn_s_barrier();                  // all waves done reading buf c
        __builtin_amdgcn_sched_barrier(0);
        c ^= 1;
    }

    if (isQ) {          // -> A with phases (log2e folded)
        #pragma unroll
        for (int j = 0; j < 4; ++j) {
            const int col = n0 + wn * 64 + j * 16 + lr;
            const float w0 = Wp[col * 3], w1 = Wp[col * 3 + 1], w2 = Wp[col * 3 + 2];
            const float bpd = bp[col], bi = bq[col];
            const int hh = col >> 6, dh = col & 63;
            #pragma unroll
            for (int i = 0; i < 4; ++i)
                #pragma unroll
                for (int rr = 0; rr < 4; ++rr) {
                    const int row = m0 + wm * 64 + i * 16 + lg * 4 + rr;
                    const int ns = row >> 10, l = row & 1023;
                    const float p = Pph[row * 3] * w0 + Pph[row * 3 + 1] * w1
                                  + Pph[row * 3 + 2] * w2 + bpd;
                    float sn, cs;
                    __sincosf(p, &sn, &cs);
                    const float v = acc[i][j][rr] + bi;
                    const size_t e = (((size_t)(ns * HN + hh)) * LQ + l) * DE + dh;
                    Abf[e]      = f2bf(v * sn * LOG2E);
                    Abf[e + 64] = f2bf(-v * cs * LOG2E);
                }
        }
    } else if (n0 < 512) {    // K half -> B with phases
        #pragma unroll
        for (int j = 0; j < 4; ++j) {
            const int col = n0 + wn * 64 + j * 16 + lr;
            const float w0 = Wp[col * 3], w1 = Wp[col * 3 + 1], w2 = Wp[col * 3 + 2];
            const float bi = bk[col];
            const int hh = col >> 6, dh = col & 63;
            #pragma unroll
            for (int i = 0; i < 4; ++i)
                #pragma unroll
                for (int rr = 0; rr < 4; ++rr) {
                    const int row = m0 + wm * 64 + i * 16 + lg * 4 + rr;
                    const int ns = row >> 10, l = row & 1023;
                    const float p = Pph[row * 3] * w0 + Pph[row * 3 + 1] * w1
                                  + Pph[row * 3 + 2] * w2;      // pk - b
                    float sn, cs;
                    __sincosf(p, &sn, &cs);
                    const float v = acc[i][j][rr] + bi;
                    const size_t e = (((size_t)(ns * HN + hh)) * LQ + l) * DE + dh;
                    Bbf[e]      = f2bf(v * cs);
                    Bbf[e + 64] = f2bf(v * sn);
                }
        }
    } else {                  // V half -> Vt (per-head transposed)
        #pragma unroll
        for (int j = 0; j < 4; ++j) {
            const int col = n0 + wn * 64 + j * 16 + lr;
            const int c2 = col - 512;
            const float bi = bv[c2];
            const int hh = c2 >> 6, dh = c2 & 63;
            #pragma unroll
            for (int i = 0; i < 4; ++i)
                #pragma unroll
                for (int rr = 0; rr < 4; ++rr) {
                    const int row = m0 + wm * 64 + i * 16 + lg * 4 + rr;
                    const int ns = row >> 10, l = row & 1023;
                    const float v = acc[i][j][rr] + bi;
                    Vtb[((size_t)((ns * HN + hh) * DHD + dh)) * LQ + l] = f2bf(v);
                }
        }
    }
}

// ---------------------------------------------------------------------------
// FFN GEMM: 128x128, BK=64, counted-vmcnt dual-barrier 2-phase dbuf.
// MODE 0: bf16 out + bias + BN partials (f32 sums)   MODE 1: bf16 out + relu
// ---------------------------------------------------------------------------
template<int MODE>
__global__ __launch_bounds__(256)
void gemm_k(const u16* __restrict__ Xb, const u16* __restrict__ W,
            const float* __restrict__ bias, void* __restrict__ out,
            int Kd, int Nn, float* __restrict__ bnp)
{
    const int m0 = blockIdx.x * 128, n0 = blockIdx.y * 128;
    const int tid = threadIdx.x;
    const int w = tid >> 6, lane = tid & 63;
    const int lr = lane & 15, lg = lane >> 4;
    const int wm = w >> 1, wn = w & 1;

    __shared__ __align__(16) u16 AsL[2][128 * 64];
    __shared__ __align__(16) u16 BsL[2][128 * 64];
    __shared__ float BnL[2][2][4][16][2];

    floatx4 acc[4][4] = {};
    const int xorp = (lr & 7) << 4;
    const int colb = lg << 4;

    auto stage = [&](int t, int b) {
        const size_t ko = (size_t)t * 64;
        #pragma unroll
        for (int r = 0; r < 4; ++r) {
            const int cid = r * 256 + tid;
            const int row = cid >> 3, c16 = cid & 7;
            const int kc = ((c16 ^ (row & 7)) << 3);
            gload16(&Xb[(size_t)(m0 + row) * Kd + ko + kc], &AsL[b][cid * 8]);
        }
        #pragma unroll
        for (int r = 0; r < 4; ++r) {
            const int cid = r * 256 + tid;
            const int row = cid >> 3, c16 = cid & 7;
            const int kc = ((c16 ^ (row & 7)) << 3);
            gload16(&W[(size_t)(n0 + row) * Kd + ko + kc], &BsL[b][cid * 8]);
        }
    };

    const int nt = Kd >> 6;
    stage(0, 0);
    int c = 0;
    for (int t = 0; t < nt; ++t) {
        if (t + 1 < nt) {
            stage(t + 1, c ^ 1);                       // 8 loads stay in flight
            asm volatile("s_waitcnt vmcnt(8)" ::: "memory");
        } else {
            asm volatile("s_waitcnt vmcnt(0)" ::: "memory");
        }
        __builtin_amdgcn_sched_barrier(0);
        __builtin_amdgcn_s_barrier();                  // buf c staged for all waves

        const char* la = (const char*)AsL[c];
        const char* lb = (const char*)BsL[c];
        __builtin_amdgcn_s_setprio(1);
        #pragma unroll
        for (int ks = 0; ks < 2; ++ks) {
            const int cb = (ks * 64 + colb) ^ xorp;
            bf16x8 a[4], b[4];
            #pragma unroll
            for (int i = 0; i < 4; ++i)
                a[i] = *(const bf16x8*)(la + (((wm * 64 + i * 16 + lr) << 7) + cb));
            #pragma unroll
            for (int j = 0; j < 4; ++j)
                b[j] = *(const bf16x8*)(lb + (((wn * 64 + j * 16 + lr) << 7) + cb));
            #pragma unroll
            for (int i = 0; i < 4; ++i)
                #pragma unroll
                for (int j = 0; j < 4; ++j)
                    acc[i][j] = __builtin_amdgcn_mfma_f32_16x16x32_bf16(a[i], b[j], acc[i][j], 0, 0, 0);
        }
        __builtin_amdgcn_s_setprio(0);
        __builtin_amdgcn_s_barrier();                  // all waves done reading buf c
        __builtin_amdgcn_sched_barrier(0);
        c ^= 1;
    }

    float bs[4], bs2[4];
    #pragma unroll
    for (int j = 0; j < 4; ++j) { bs[j] = 0.f; bs2[j] = 0.f; }
    #pragma unroll
    for (int j = 0; j < 4; ++j) {
        const int col = n0 + wn * 64 + j * 16 + lr;
        const float bi = bias[col];
        #pragma unroll
        for (int i = 0; i < 4; ++i)
            #pragma unroll
            for (int rr = 0; rr < 4; ++rr) {
                const int row = m0 + wm * 64 + i * 16 + lg * 4 + rr;
                float v = acc[i][j][rr] + bi;
                if (MODE == 1) {
                    v = fmaxf(v, 0.f);
                    ((u16*)out)[(size_t)row * Nn + col] = f2bf(v);
                } else {
                    ((u16*)out)[(size_t)row * Nn + col] = f2bf(v);
                    bs[j] += v; bs2[j] += v * v;
                }
            }
    }
    if (MODE == 0) {    // BN partial over this m-tile's 128 rows
        #pragma unroll
        for (int j = 0; j < 4; ++j) {
            float s = bs[j], s2 = bs2[j];
            s  += __shfl_xor(s, 16);  s  += __shfl_xor(s, 32);
            s2 += __shfl_xor(s2, 16); s2 += __shfl_xor(s2, 32);
            if (lg == 0) { BnL[wm][wn][j][lr][0] = s; BnL[wm][wn][j][lr][1] = s2; }
        }
        __syncthreads();
        if (tid < 128) {
            const int wn2 = tid >> 6, j2 = (tid >> 4) & 3, lr2 = tid & 15;
            const float s  = BnL[0][wn2][j2][lr2][0] + BnL[1][wn2][j2][lr2][0];
            const float s2 = BnL[0][wn2][j2][lr2][1] + BnL[1][wn2][j2][lr2][1];
            const int col = n0 + tid;
            bnp[(size_t)blockIdx.x * 512 + col]         = s;
            bnp[32768 + (size_t)blockIdx.x * 512 + col] = s2;
        }
    }
}

// ---------------------------------------------------------------------------
// Flash attention (R11-verified): 512-thr blocks (8 waves), QBLK=256,
// KVBLK=64, dual 16-q groups per wave (each kfrag/vfrag feeds 2 MFMA).
// 256 blocks = 1/CU. No-max softmax; counted-vmcnt dual-barrier.
// ---------------------------------------------------------------------------
__global__ __launch_bounds__(512, 2)
void attn_mfma(const u16* __restrict__ Ag, const u16* __restrict__ Bg,
               const u16* __restrict__ Vtg, u16* __restrict__ Tbf)
{
    int bid = blockIdx.x;
    bid = (bid & 7) * 32 + (bid >> 3);    // XCD swizzle (256 % 8 == 0): 8 heads/XCD
    const int head = bid >> 2;            // 0..63
    const int row0 = (bid & 3) * 256;
    const int ns = head >> 3, h = head & 7;
    const int tid = threadIdx.x, w = tid >> 6, lane = tid & 63;
    const int lr = lane & 15, lg = lane >> 4;

    __shared__ __align__(16) u16 BsL[2][64 * 128];   // 32 KB
    __shared__ __align__(16) u16 VtL[2][64 * 64];    // 16 KB
    __shared__ __align__(16) u16 Ps[8][32][72];      // 36 KB

    // Q fragments -> registers: group A rows w*32+lr, group B rows w*32+16+lr
    bf16x8 qfA[4], qfB[4];
    {
        const size_t rb = ((size_t)head * LQ + row0 + w * 32 + lr) * DE;
        #pragma unroll
        for (int ks = 0; ks < 4; ++ks) {
            qfA[ks] = *(const bf16x8*)&Ag[rb + ks * 32 + lg * 8];
            qfB[ks] = *(const bf16x8*)&Ag[rb + 16 * DE + ks * 32 + lg * 8];
        }
    }

    auto stageBV = [&](int kt, int b) {
        #pragma unroll
        for (int r = 0; r < 2; ++r) {                 // B tile 16 KB
            const int cid = r * 512 + tid;
            const int row = cid >> 4, c16 = cid & 15;
            const int kc = ((c16 ^ (row & 7)) << 3);
            gload16(&Bg[((size_t)head * LQ + kt * 64 + row) * DE + kc], &BsL[b][cid * 8]);
        }
        {                                             // Vt tile 8 KB
            const int row = tid >> 3, c16 = tid & 7;
            const int kc = ((c16 ^ (row & 7)) << 3);
            gload16(&Vtg[((size_t)head * DHD + row) * LQ + kt * 64 + kc], &VtL[b][tid * 8]);
        }
    };
    stageBV(0, 0);

    floatx4 oA[4] = {}, oB[4] = {};
    float lsA = 0.f, lsB = 0.f;
    const int xorp = (lr & 7) << 4;
    const int colb = lg << 4;
    int c = 0;

    for (int kt = 0; kt < 16; ++kt) {
        if (kt < 15) {
            stageBV(kt + 1, c ^ 1);                   // 3 loads stay in flight
            asm volatile("s_waitcnt vmcnt(3)" ::: "memory");
        } else {
            asm volatile("s_waitcnt vmcnt(0)" ::: "memory");
        }
        __builtin_amdgcn_sched_barrier(0);
        __builtin_amdgcn_s_barrier();                 // tile kt staged for all waves

        const char* lb = (const char*)BsL[c];
        const char* lv = (const char*)VtL[c];

        // ---- S^T strips, kfrag shared across both q-groups ----
        floatx4 sA[4] = {}, sB[4] = {};
        __builtin_amdgcn_s_setprio(1);
        #pragma unroll
        for (int ks = 0; ks < 4; ++ks) {
            const int cb = (ks * 64 + colb) ^ xorp;
            bf16x8 kf[4];
            #pragma unroll
            for (int j = 0; j < 4; ++j)
                kf[j] = *(const bf16x8*)(lb + (((j * 16 + lr) << 8) + cb));
            #pragma unroll
            for (int j = 0; j < 4; ++j) {
                sA[j] = __builtin_amdgcn_mfma_f32_16x16x32_bf16(kf[j], qfA[ks], sA[j], 0, 0, 0);
                sB[j] = __builtin_amdgcn_mfma_f32_16x16x32_bf16(kf[j], qfB[ks], sB[j], 0, 0, 0);
            }
        }
        __builtin_amdgcn_s_setprio(0);

        // ---- no-max softmax ----
        float tsa = 0.f, tsb = 0.f;
        #pragma unroll
        for (int j = 0; j < 4; ++j)
            #pragma unroll
            for (int r = 0; r < 4; ++r) {
                float ea = exp2f(sA[j][r]); sA[j][r] = ea; tsa += ea;
                float eb = exp2f(sB[j][r]); sB[j][r] = eb; tsb += eb;
            }
        lsA += tsa; lsB += tsb;

        // ---- P -> per-wave LDS (cvt_pk), rows 0-15 = A, 16-31 = B ----
        #pragma unroll
        for (int j = 0; j < 4; ++j) {
            unsigned plo, phi;
            asm("v_cvt_pk_bf16_f32 %0, %1, %2" : "=v"(plo) : "v"(sA[j][0]), "v"(sA[j][1]));
            asm("v_cvt_pk_bf16_f32 %0, %1, %2" : "=v"(phi) : "v"(sA[j][2]), "v"(sA[j][3]));
            uint2 pv; pv.x = plo; pv.y = phi;
            *(uint2*)&Ps[w][lr][j * 16 + lg * 4] = pv;
            asm("v_cvt_pk_bf16_f32 %0, %1, %2" : "=v"(plo) : "v"(sB[j][0]), "v"(sB[j][1]));
            asm("v_cvt_pk_bf16_f32 %0, %1, %2" : "=v"(phi) : "v"(sB[j][2]), "v"(sB[j][3]));
            pv.x = plo; pv.y = phi;
            *(uint2*)&Ps[w][16 + lr][j * 16 + lg * 4] = pv;
        }

        // ---- PV: vfrag shared across both q-groups ----
        __builtin_amdgcn_s_setprio(1);
        #pragma unroll
        for (int ks2 = 0; ks2 < 2; ++ks2) {
            const int cb = (ks2 * 64 + colb) ^ xorp;
            bf16x8 pfA = *(const bf16x8*)&Ps[w][lr][ks2 * 32 + lg * 8];
            bf16x8 pfB = *(const bf16x8*)&Ps[w][16 + lr][ks2 * 32 + lg * 8];
            #pragma unroll
            for (int m = 0; m < 4; ++m) {
                bf16x8 vf = *(const bf16x8*)(lv + (((m * 16 + lr) << 7) + cb));
                oA[m] = __builtin_amdgcn_mfma_f32_16x16x32_bf16(vf, pfA, oA[m], 0, 0, 0);
                oB[m] = __builtin_amdgcn_mfma_f32_16x16x32_bf16(vf, pfB, oB[m], 0, 0, 0);
            }
        }
        __builtin_amdgcn_s_setprio(0);
        __builtin_amdgcn_s_barrier();                 // all waves done with buf c
        __builtin_amdgcn_sched_barrier(0);
        c ^= 1;
    }

    // denominators (once), normalize, write merged-head T (bf16)
    lsA += __shfl_xor(lsA, 16); lsA += __shfl_xor(lsA, 32);
    lsB += __shfl_xor(lsB, 16); lsB += __shfl_xor(lsB, 32);
    const float invA = 1.f / lsA, invB = 1.f / lsB;
    const size_t trA = ((size_t)ns * LQ + row0 + w * 32 + lr) * DM + h * DHD;
    const size_t trB = trA + (size_t)16 * DM;
    #pragma unroll
    for (int m = 0; m < 4; ++m) {
        union { u16 u[4]; uint2 v; } pk;
        pk.u[0] = f2bf(oA[m][0] * invA); pk.u[1] = f2bf(oA[m][1] * invA);
        pk.u[2] = f2bf(oA[m][2] * invA); pk.u[3] = f2bf(oA[m][3] * invA);
        *(uint2*)&Tbf[trA + m * 16 + lg * 4] = pk.v;
        pk.u[0] = f2bf(oB[m][0] * invB); pk.u[1] = f2bf(oB[m][1] * invB);
        pk.u[2] = f2bf(oB[m][2] * invB); pk.u[3] = f2bf(oB[m][3] * invB);
        *(uint2*)&Tbf[trB + m * 16 + lg * 4] = pk.v;
    }
}

// ---------------------------------------------------------------------------
// BN: reduce per-block partials (64 m-blocks) -> stats; then final
// (Y is bf16 now; f32 stats; float4-wide output)
// ---------------------------------------------------------------------------
__global__ __launch_bounds__(256)
void bn_reduce(const float* __restrict__ part, float* __restrict__ stats)
{
    const int cx = blockIdx.x * 256 + threadIdx.x;   // 0..511
    float s = 0.f, s2 = 0.f;
    for (int b = 0; b < 64; ++b) {
        s  += part[(size_t)b * 512 + cx];
        s2 += part[32768 + (size_t)b * 512 + cx];
    }
    stats[cx] = s;
    stats[512 + cx] = s2;
}

__global__ __launch_bounds__(256)
void bn_final(const u16* __restrict__ Y, const float* __restrict__ Qin,
              const float* __restrict__ stats,
              const float* __restrict__ gamma, const float* __restrict__ beta,
              float* __restrict__ out)
{
    const int i4 = blockIdx.x * 256 + threadIdx.x;   // 0..ROWS*DM/4-1
    const int c4 = (i4 & 127) * 4;                   // channel base
    const float4 sm  = *(const float4*)&stats[c4];
    const float4 sq  = *(const float4*)&stats[512 + c4];
    const float4 gm  = *(const float4*)&gamma[c4];
    const float4 bt  = *(const float4*)&beta[c4];
    union { u16 u[4]; uint2 v; } yv;
    yv.v = *(const uint2*)&Y[(size_t)i4 * 4];
    const float4 q   = *(const float4*)&Qin[(size_t)i4 * 4];
    float4 o;
    {
        const float mu = sm.x * (1.f / ROWS);
        const float rs = rsqrtf(sq.x * (1.f / ROWS) - mu * mu + 1e-5f);
        o.x = q.x + (bf2f(yv.u[0]) - mu) * rs * gm.x + bt.x;
    }
    {
        const float mu = sm.y * (1.f / ROWS);
        const float rs = rsqrtf(sq.y * (1.f / ROWS) - mu * mu + 1e-5f);
        o.y = q.y + (bf2f(yv.u[1]) - mu) * rs * gm.y + bt.y;
    }
    {
        const float mu = sm.z * (1.f / ROWS);
        const float rs = rsqrtf(sq.z * (1.f / ROWS) - mu * mu + 1e-5f);
        o.z = q.z + (bf2f(yv.u[2]) - mu) * rs * gm.z + bt.z;
    }
    {
        const float mu = sm.w * (1.f / ROWS);
        const float rs = rsqrtf(sq.w * (1.f / ROWS) - mu * mu + 1e-5f);
        o.w = q.w + (bf2f(yv.u[3]) - mu) * rs * gm.w + bt.w;
    }
    *(float4*)&out[(size_t)i4 * 4] = o;
}

// ---------------------------------------------------------------------------
extern "C" void kernel_launch(void* const* d_in, const int* in_sizes, int n_in,
                              void* d_out, int out_size, void* d_ws, size_t ws_size,
                              hipStream_t stream)
{
    (void)in_sizes; (void)n_in; (void)out_size; (void)ws_size;

    const float* Q    = (const float*)d_in[0];
    const float* K    = (const float*)d_in[1];
    const float* Pq   = (const float*)d_in[2];
    const float* Pk   = (const float*)d_in[3];
    const float* Wq   = (const float*)d_in[4];
    const float* bq   = (const float*)d_in[5];
    const float* Wk   = (const float*)d_in[6];
    const float* bk   = (const float*)d_in[7];
    const float* Wv   = (const float*)d_in[8];
    const float* bv   = (const float*)d_in[9];
    const float* Wp   = (const float*)d_in[10];
    const float* bp   = (const float*)d_in[11];
    const float* We   = (const float*)d_in[12];
    const float* be   = (const float*)d_in[13];
    const float* Wc   = (const float*)d_in[14];
    const float* bc   = (const float*)d_in[15];
    const float* gamma= (const float*)d_in[16];
    const float* beta = (const float*)d_in[17];

    const size_t MB = 1u << 20;
    char* w8 = (char*)d_ws;
    u16*  Abf  = (u16*)(w8);                  // 16 MB (A operands)
    u16*  Bbf  = (u16*)(w8 + 16 * MB);        // 16 MB
    u16*  Vtb  = (u16*)(w8 + 32 * MB);        //  8 MB
    u16*  Tbf  = (u16*)(w8 + 40 * MB);        //  8 MB
    u16*  H1b  = (u16*)(w8 + 48 * MB);        // 16 MB
    u16*  Qbf  = (u16*)(w8 + 64 * MB);        //  8 MB
    u16*  Kbf  = (u16*)(w8 + 72 * MB);        //  8 MB
    u16*  Ybf  = (u16*)(w8);                  //  8 MB (reuses Abf after attn)
    float* part  = (float*)(w8 + 16 * MB);    // 256 KB (reuses Bbf after attn)
    float* stats = (float*)(w8 + 17 * MB);    //  4 KB
    u16*  Wqb  = (u16*)(w8 + 80 * MB);                    // 0.5 MB
    u16*  Wkvb = (u16*)(w8 + 80 * MB + 512 * 1024);       // 1 MB
    u16*  Web  = (u16*)(w8 + 80 * MB + 1536 * 1024);      // 1 MB
    u16*  Wcb  = (u16*)(w8 + 80 * MB + 2560 * 1024);      // 1 MB

    dim3 blk256(256);

    // one fused cast: weights + Q + K
    castall<<<4992, blk256, 0, stream>>>(Wq, Wk, Wv, We, Wc, Q, K,
                                         Wqb, Wkvb, Web, Wcb, Qbf, Kbf);

    // fused Q-proj + KV-proj (one dispatch, 768 blocks, pure gload_lds path)
    proj_qkv<<<dim3(64, 12), blk256, 0, stream>>>(Qbf, Kbf, Wqb, Wkvb,
        bq, bk, bv, Abf, Bbf, Vtb, Pq, Pk, Wp, bp);

    // flash attention (256 blocks x 8 waves, dual-group, 1 block/CU)
    attn_mfma<<<256, dim3(512), 0, stream>>>(Abf, Bbf, Vtb, Tbf);

    // FFN (Y emitted as bf16 + f32 BN partials)
    gemm_k<1><<<dim3(64, 8), blk256, 0, stream>>>(Tbf, Web, be, H1b, DM, 2 * DM, nullptr);
    gemm_k<0><<<dim3(64, 4), blk256, 0, stream>>>(H1b, Wcb, bc, Ybf, 2 * DM, DM, part);

    // BN stats + final
    bn_reduce<<<2, blk256, 0, stream>>>(part, stats);
    bn_final<<<ROWS * DM / 1024, blk256, 0, stream>>>(Ybf, Q, stats, gamma, beta,
                                                      (float*)d_out);
}

// Round 14
// 139.104 us; speedup vs baseline: 1.1113x; 1.0148x over previous
//
#include <hip/hip_runtime.h>
#include <math.h>

#define LQ 1024      // sequence length L
#define DM 512       // model dim D
#define HN 8         // heads
#define DHD 64       // head dim
#define ROWS 8192    // N*S*L
#define DE 128       // effective attention dim (2*DHD)
#define LOG2E 1.44269504088896f

typedef __attribute__((ext_vector_type(8))) short bf16x8;
typedef __attribute__((ext_vector_type(4))) float floatx4;
typedef unsigned short u16;

static __device__ __forceinline__ u16 f2bf(float x) {
    unsigned int u = __float_as_uint(x);
    u = (u + 0x7fffu + ((u >> 16) & 1u)) >> 16;   // round-nearest-even
    return (u16)u;
}

static __device__ __forceinline__ float bf2f(u16 u) {
    return __uint_as_float(((unsigned)u) << 16);
}

static __device__ __forceinline__ void gload16(const void* g, void* l) {
    __builtin_amdgcn_global_load_lds((const __attribute__((address_space(1))) void*)g,
                                     (__attribute__((address_space(3))) void*)l,
                                     16, 0, 0);
}

static __device__ __forceinline__ void cvt8(const float* s, u16* d, size_t o) {
    const float4* sp = (const float4*)s + 2 * o;
    float4 a = sp[0], b = sp[1];
    union { u16 u[8]; uint4 v; } ov;
    ov.u[0]=f2bf(a.x); ov.u[1]=f2bf(a.y); ov.u[2]=f2bf(a.z); ov.u[3]=f2bf(a.w);
    ov.u[4]=f2bf(b.x); ov.u[5]=f2bf(b.y); ov.u[6]=f2bf(b.z); ov.u[7]=f2bf(b.w);
    ((uint4*)d)[o] = ov.v;
}

// ---------------------------------------------------------------------------
// one fused cast dispatch: all weights + Q + K  (memory-bound)
// ---------------------------------------------------------------------------
__global__ __launch_bounds__(256)
void castall(const float* __restrict__ Wq, const float* __restrict__ Wk,
             const float* __restrict__ Wv, const float* __restrict__ We,
             const float* __restrict__ Wc, const float* __restrict__ Q,
             const float* __restrict__ K,
             u16* __restrict__ Wqb, u16* __restrict__ Wkvb,
             u16* __restrict__ Web, u16* __restrict__ Wcb,
             u16* __restrict__ Qb, u16* __restrict__ Kb)
{
    int i = blockIdx.x * 256 + threadIdx.x;      // vec8 id, total 1277952
    const float* s; u16* d; int o;
    if (i < 32768)        { s = Wq; d = Wqb;            o = i; }
    else if (i < 65536)   { s = Wk; d = Wkvb;           o = i - 32768; }
    else if (i < 98304)   { s = Wv; d = Wkvb + 262144;  o = i - 65536; }
    else if (i < 163840)  { s = We; d = Web;            o = i - 98304; }
    else if (i < 229376)  { s = Wc; d = Wcb;            o = i - 163840; }
    else if (i < 753664)  { s = Q;  d = Qb;             o = i - 229376; }
    else                  { s = K;  d = Kb;             o = i - 753664; }
    cvt8(s, d, (size_t)o);
}

// ---------------------------------------------------------------------------
// Fused projection GEMM: one dispatch, grid (64, 12).
// blockIdx.y < 4 : Q-proj -> A (sin/cos, log2e folded)
// blockIdx.y >= 4: KV-proj -> B (n0<512) / Vt (n0>=512, per-head transposed)
// 128x128 tile, BK=64, counted-vmcnt dual-barrier 2-phase dbuf,
// pure global_load_lds staging w/ XOR swizzle. Kd = 512 for both paths.
// ---------------------------------------------------------------------------
__global__ __launch_bounds__(256)
void proj_qkv(const u16* __restrict__ Qb, const u16* __restrict__ Kb,
              const u16* __restrict__ Wqb, const u16* __restrict__ Wkvb,
              const float* __restrict__ bq, const float* __restrict__ bk,
              const float* __restrict__ bv,
              u16* __restrict__ Abf, u16* __restrict__ Bbf, u16* __restrict__ Vtb,
              const float* __restrict__ Pq, const float* __restrict__ Pk,
              const float* __restrict__ Wp, const float* __restrict__ bp)
{
    const bool isQ = blockIdx.y < 4;
    const int m0 = blockIdx.x * 128;
    const int n0 = (isQ ? blockIdx.y : blockIdx.y - 4) * 128;
    const u16* Xb = isQ ? Qb : Kb;
    const u16* W  = isQ ? Wqb : Wkvb;
    const float* Pph = isQ ? Pq : Pk;
    const int Kd = DM;

    const int tid = threadIdx.x;
    const int w = tid >> 6, lane = tid & 63;
    const int lr = lane & 15, lg = lane >> 4;
    const int wm = w >> 1, wn = w & 1;

    __shared__ __align__(16) u16 AsL[2][128 * 64];
    __shared__ __align__(16) u16 BsL[2][128 * 64];

    floatx4 acc[4][4] = {};
    const int xorp = (lr & 7) << 4;
    const int colb = lg << 4;

    auto stage = [&](int t, int b) {
        const size_t ko = (size_t)t * 64;
        #pragma unroll
        for (int r = 0; r < 4; ++r) {
            const int cid = r * 256 + tid;
            const int row = cid >> 3, c16 = cid & 7;
            const int kc = ((c16 ^ (row & 7)) << 3);
            gload16(&Xb[(size_t)(m0 + row) * Kd + ko + kc], &AsL[b][cid * 8]);
        }
        #pragma unroll
        for (int r = 0; r < 4; ++r) {
            const int cid = r * 256 + tid;
            const int row = cid >> 3, c16 = cid & 7;
            const int kc = ((c16 ^ (row & 7)) << 3);
            gload16(&W[(size_t)(n0 + row) * Kd + ko + kc], &BsL[b][cid * 8]);
        }
    };

    const int nt = Kd >> 6;
    stage(0, 0);
    int c = 0;
    for (int t = 0; t < nt; ++t) {
        if (t + 1 < nt) {
            stage(t + 1, c ^ 1);                       // 8 loads stay in flight
            asm volatile("s_waitcnt vmcnt(8)" ::: "memory");
        } else {
            asm volatile("s_waitcnt vmcnt(0)" ::: "memory");
        }
        __builtin_amdgcn_sched_barrier(0);
        __builtin_amdgcn_s_barrier();                  // buf c staged for all waves

        const char* la = (const char*)AsL[c];
        const char* lb = (const char*)BsL[c];
        __builtin_amdgcn_s_setprio(1);
        #pragma unroll
        for (int ks = 0; ks < 2; ++ks) {
            const int cb = (ks * 64 + colb) ^ xorp;
            bf16x8 a[4], b[4];
            #pragma unroll
            for (int i = 0; i < 4; ++i)
                a[i] = *(const bf16x8*)(la + (((wm * 64 + i * 16 + lr) << 7) + cb));
            #pragma unroll
            for (int j = 0; j < 4; ++j)
                b[j] = *(const bf16x8*)(lb + (((wn * 64 + j * 16 + lr) << 7) + cb));
            #pragma unroll
            for (int i = 0; i < 4; ++i)
                #pragma unroll
                for (int j = 0; j < 4; ++j)
                    acc[i][j] = __builtin_amdgcn_mfma_f32_16x16x32_bf16(a[i], b[j], acc[i][j], 0, 0, 0);
        }
        __builtin_amdgcn_s_setprio(0);
        __builtin_amdgcn_s_barrier();                  // all waves done reading buf c
        __builtin_amdgcn_sched_barrier(0);
        c ^= 1;
    }

    if (isQ) {          // -> A with phases (log2e folded)
        #pragma unroll
        for (int j = 0; j < 4; ++j) {
            const int col = n0 + wn * 64 + j * 16 + lr;
            const float w0 = Wp[col * 3], w1 = Wp[col * 3 + 1], w2 = Wp[col * 3 + 2];
            const float bpd = bp[col], bi = bq[col];
            const int hh = col >> 6, dh = col & 63;
            #pragma unroll
            for (int i = 0; i < 4; ++i)
                #pragma unroll
                for (int rr = 0; rr < 4; ++rr) {
                    const int row = m0 + wm * 64 + i * 16 + lg * 4 + rr;
                    const int ns = row >> 10, l = row & 1023;
                    const float p = Pph[row * 3] * w0 + Pph[row * 3 + 1] * w1
                                  + Pph[row * 3 + 2] * w2 + bpd;
                    float sn, cs;
                    __sincosf(p, &sn, &cs);
                    const float v = acc[i][j][rr] + bi;
                    const size_t e = (((size_t)(ns * HN + hh)) * LQ + l) * DE + dh;
                    Abf[e]      = f2bf(v * sn * LOG2E);
                    Abf[e + 64] = f2bf(-v * cs * LOG2E);
                }
        }
    } else if (n0 < 512) {    // K half -> B with phases
        #pragma unroll
        for (int j = 0; j < 4; ++j) {
            const int col = n0 + wn * 64 + j * 16 + lr;
            const float w0 = Wp[col * 3], w1 = Wp[col * 3 + 1], w2 = Wp[col * 3 + 2];
            const float bi = bk[col];
            const int hh = col >> 6, dh = col & 63;
            #pragma unroll
            for (int i = 0; i < 4; ++i)
                #pragma unroll
                for (int rr = 0; rr < 4; ++rr) {
                    const int row = m0 + wm * 64 + i * 16 + lg * 4 + rr;
                    const int ns = row >> 10, l = row & 1023;
                    const float p = Pph[row * 3] * w0 + Pph[row * 3 + 1] * w1
                                  + Pph[row * 3 + 2] * w2;      // pk - b
                    float sn, cs;
                    __sincosf(p, &sn, &cs);
                    const float v = acc[i][j][rr] + bi;
                    const size_t e = (((size_t)(ns * HN + hh)) * LQ + l) * DE + dh;
                    Bbf[e]      = f2bf(v * cs);
                    Bbf[e + 64] = f2bf(v * sn);
                }
        }
    } else {                  // V half -> Vt (per-head transposed)
        #pragma unroll
        for (int j = 0; j < 4; ++j) {
            const int col = n0 + wn * 64 + j * 16 + lr;
            const int c2 = col - 512;
            const float bi = bv[c2];
            const int hh = c2 >> 6, dh = c2 & 63;
            #pragma unroll
            for (int i = 0; i < 4; ++i)
                #pragma unroll
                for (int rr = 0; rr < 4; ++rr) {
                    const int row = m0 + wm * 64 + i * 16 + lg * 4 + rr;
                    const int ns = row >> 10, l = row & 1023;
                    const float v = acc[i][j][rr] + bi;
                    Vtb[((size_t)((ns * HN + hh) * DHD + dh)) * LQ + l] = f2bf(v);
                }
        }
    }
}

// ---------------------------------------------------------------------------
// FFN GEMM: 128x128, BK=64, counted-vmcnt dual-barrier 2-phase dbuf.
// MODE 0: bf16 out + bias + BN partials (f32 sums)   MODE 1: bf16 out + relu
// ---------------------------------------------------------------------------
template<int MODE>
__global__ __launch_bounds__(256)
void gemm_k(const u16* __restrict__ Xb, const u16* __restrict__ W,
            const float* __restrict__ bias, void* __restrict__ out,
            int Kd, int Nn, float* __restrict__ bnp)
{
    const int m0 = blockIdx.x * 128, n0 = blockIdx.y * 128;
    const int tid = threadIdx.x;
    const int w = tid >> 6, lane = tid & 63;
    const int lr = lane & 15, lg = lane >> 4;
    const int wm = w >> 1, wn = w & 1;

    __shared__ __align__(16) u16 AsL[2][128 * 64];
    __shared__ __align__(16) u16 BsL[2][128 * 64];
    __shared__ float BnL[2][2][4][16][2];

    floatx4 acc[4][4] = {};
    const int xorp = (lr & 7) << 4;
    const int colb = lg << 4;

    auto stage = [&](int t, int b) {
        const size_t ko = (size_t)t * 64;
        #pragma unroll
        for (int r = 0; r < 4; ++r) {
            const int cid = r * 256 + tid;
            const int row = cid >> 3, c16 = cid & 7;
            const int kc = ((c16 ^ (row & 7)) << 3);
            gload16(&Xb[(size_t)(m0 + row) * Kd + ko + kc], &AsL[b][cid * 8]);
        }
        #pragma unroll
        for (int r = 0; r < 4; ++r) {
            const int cid = r * 256 + tid;
            const int row = cid >> 3, c16 = cid & 7;
            const int kc = ((c16 ^ (row & 7)) << 3);
            gload16(&W[(size_t)(n0 + row) * Kd + ko + kc], &BsL[b][cid * 8]);
        }
    };

    const int nt = Kd >> 6;
    stage(0, 0);
    int c = 0;
    for (int t = 0; t < nt; ++t) {
        if (t + 1 < nt) {
            stage(t + 1, c ^ 1);                       // 8 loads stay in flight
            asm volatile("s_waitcnt vmcnt(8)" ::: "memory");
        } else {
            asm volatile("s_waitcnt vmcnt(0)" ::: "memory");
        }
        __builtin_amdgcn_sched_barrier(0);
        __builtin_amdgcn_s_barrier();                  // buf c staged for all waves

        const char* la = (const char*)AsL[c];
        const char* lb = (const char*)BsL[c];
        __builtin_amdgcn_s_setprio(1);
        #pragma unroll
        for (int ks = 0; ks < 2; ++ks) {
            const int cb = (ks * 64 + colb) ^ xorp;
            bf16x8 a[4], b[4];
            #pragma unroll
            for (int i = 0; i < 4; ++i)
                a[i] = *(const bf16x8*)(la + (((wm * 64 + i * 16 + lr) << 7) + cb));
            #pragma unroll
            for (int j = 0; j < 4; ++j)
                b[j] = *(const bf16x8*)(lb + (((wn * 64 + j * 16 + lr) << 7) + cb));
            #pragma unroll
            for (int i = 0; i < 4; ++i)
                #pragma unroll
                for (int j = 0; j < 4; ++j)
                    acc[i][j] = __builtin_amdgcn_mfma_f32_16x16x32_bf16(a[i], b[j], acc[i][j], 0, 0, 0);
        }
        __builtin_amdgcn_s_setprio(0);
        __builtin_amdgcn_s_barrier();                  // all waves done reading buf c
        __builtin_amdgcn_sched_barrier(0);
        c ^= 1;
    }

    float bs[4], bs2[4];
    #pragma unroll
    for (int j = 0; j < 4; ++j) { bs[j] = 0.f; bs2[j] = 0.f; }
    #pragma unroll
    for (int j = 0; j < 4; ++j) {
        const int col = n0 + wn * 64 + j * 16 + lr;
        const float bi = bias[col];
        #pragma unroll
        for (int i = 0; i < 4; ++i)
            #pragma unroll
            for (int rr = 0; rr < 4; ++rr) {
                const int row = m0 + wm * 64 + i * 16 + lg * 4 + rr;
                float v = acc[i][j][rr] + bi;
                if (MODE == 1) {
                    v = fmaxf(v, 0.f);
                    ((u16*)out)[(size_t)row * Nn + col] = f2bf(v);
                } else {
                    ((u16*)out)[(size_t)row * Nn + col] = f2bf(v);
                    bs[j] += v; bs2[j] += v * v;
                }
            }
    }
    if (MODE == 0) {    // BN partial over this m-tile's 128 rows
        #pragma unroll
        for (int j = 0; j < 4; ++j) {
            float s = bs[j], s2 = bs2[j];
            s  += __shfl_xor(s, 16);  s  += __shfl_xor(s, 32);
            s2 += __shfl_xor(s2, 16); s2 += __shfl_xor(s2, 32);
            if (lg == 0) { BnL[wm][wn][j][lr][0] = s; BnL[wm][wn][j][lr][1] = s2; }
        }
        __syncthreads();
        if (tid < 128) {
            const int wn2 = tid >> 6, j2 = (tid >> 4) & 3, lr2 = tid & 15;
            const float s  = BnL[0][wn2][j2][lr2][0] + BnL[1][wn2][j2][lr2][0];
            const float s2 = BnL[0][wn2][j2][lr2][1] + BnL[1][wn2][j2][lr2][1];
            const int col = n0 + tid;
            bnp[(size_t)blockIdx.x * 512 + col]         = s;
            bnp[32768 + (size_t)blockIdx.x * 512 + col] = s2;
        }
    }
}

// ---------------------------------------------------------------------------
// Flash attention: 512-thr blocks (8 waves), QBLK=256, KVBLK=128 (halved
// barrier count: 8 tiles x 2 barriers). Dual 16-q groups per wave. PV runs
// as two 64-key half-passes through the per-wave Ps buffer (wave-ordered DS
// ops, no extra barriers). Counted-vmcnt (6 staging loads in flight).
// LDS 133 KB, 1 block/CU.
// ---------------------------------------------------------------------------
__global__ __launch_bounds__(512, 2)
void attn_mfma(const u16* __restrict__ Ag, const u16* __restrict__ Bg,
               const u16* __restrict__ Vtg, u16* __restrict__ Tbf)
{
    int bid = blockIdx.x;
    bid = (bid & 7) * 32 + (bid >> 3);    // XCD swizzle (256 % 8 == 0): 8 heads/XCD
    const int head = bid >> 2;            // 0..63
    const int row0 = (bid & 3) * 256;
    const int ns = head >> 3, h = head & 7;
    const int tid = threadIdx.x, w = tid >> 6, lane = tid & 63;
    const int lr = lane & 15, lg = lane >> 4;

    __shared__ __align__(16) u16 BsL[2][128 * 128];  // 64 KB (K tiles, 128 keys)
    __shared__ __align__(16) u16 VtL[2][64 * 128];   // 32 KB (Vt, 128 keys)
    __shared__ __align__(16) u16 Ps[8][32][72];      // 36 KB (per-wave, 64 keys)

    // Q fragments -> registers: group A rows w*32+lr, group B rows w*32+16+lr
    bf16x8 qfA[4], qfB[4];
    {
        const size_t rb = ((size_t)head * LQ + row0 + w * 32 + lr) * DE;
        #pragma unroll
        for (int ks = 0; ks < 4; ++ks) {
            qfA[ks] = *(const bf16x8*)&Ag[rb + ks * 32 + lg * 8];
            qfB[ks] = *(const bf16x8*)&Ag[rb + 16 * DE + ks * 32 + lg * 8];
        }
    }

    auto stageKV = [&](int kt, int b) {
        #pragma unroll
        for (int r = 0; r < 4; ++r) {                 // K tile 32 KB (2048 granules)
            const int cid = r * 512 + tid;
            const int row = cid >> 4, c16 = cid & 15;
            const int kc = ((c16 ^ (row & 7)) << 3);
            gload16(&Bg[((size_t)head * LQ + kt * 128 + row) * DE + kc], &BsL[b][cid * 8]);
        }
        #pragma unroll
        for (int r = 0; r < 2; ++r) {                 // Vt tile 16 KB (1024 granules)
            const int cid = r * 512 + tid;
            const int row = cid >> 4, c16 = cid & 15;
            const int kc = ((c16 ^ (row & 7)) << 3);
            gload16(&Vtg[((size_t)head * DHD + row) * LQ + kt * 128 + kc], &VtL[b][cid * 8]);
        }
    };
    stageKV(0, 0);

    floatx4 oA[4] = {}, oB[4] = {};
    float lsA = 0.f, lsB = 0.f;
    const int xorp = (lr & 7) << 4;
    const int colb = lg << 4;
    int c = 0;

    for (int kt = 0; kt < 8; ++kt) {
        if (kt < 7) {
            stageKV(kt + 1, c ^ 1);                   // 6 loads stay in flight
            asm volatile("s_waitcnt vmcnt(6)" ::: "memory");
        } else {
            asm volatile("s_waitcnt vmcnt(0)" ::: "memory");
        }
        __builtin_amdgcn_sched_barrier(0);
        __builtin_amdgcn_s_barrier();                 // tile kt staged for all waves

        const char* lb = (const char*)BsL[c];
        const char* lv = (const char*)VtL[c];

        // ---- S^T strips (128 keys), kfrag shared across both q-groups ----
        floatx4 sA[8] = {}, sB[8] = {};
        __builtin_amdgcn_s_setprio(1);
        #pragma unroll
        for (int ks = 0; ks < 4; ++ks) {
            const int cb = (ks * 64 + colb) ^ xorp;
            #pragma unroll
            for (int j = 0; j < 8; ++j) {
                bf16x8 kf = *(const bf16x8*)(lb + (((j * 16 + lr) << 8) + cb));
                sA[j] = __builtin_amdgcn_mfma_f32_16x16x32_bf16(kf, qfA[ks], sA[j], 0, 0, 0);
                sB[j] = __builtin_amdgcn_mfma_f32_16x16x32_bf16(kf, qfB[ks], sB[j], 0, 0, 0);
            }
        }
        __builtin_amdgcn_s_setprio(0);

        // ---- no-max softmax over all 128 keys ----
        float tsa = 0.f, tsb = 0.f;
        #pragma unroll
        for (int j = 0; j < 8; ++j)
            #pragma unroll
            for (int r = 0; r < 4; ++r) {
                float ea = exp2f(sA[j][r]); sA[j][r] = ea; tsa += ea;
                float eb = exp2f(sB[j][r]); sB[j][r] = eb; tsb += eb;
            }
        lsA += tsa; lsB += tsb;

        // ---- two 64-key half-passes through per-wave Ps (no barriers) ----
        #pragma unroll
        for (int hp = 0; hp < 2; ++hp) {
            #pragma unroll
            for (int j = 0; j < 4; ++j) {
                const int jj = hp * 4 + j;
                unsigned plo, phi;
                asm("v_cvt_pk_bf16_f32 %0, %1, %2" : "=v"(plo) : "v"(sA[jj][0]), "v"(sA[jj][1]));
                asm("v_cvt_pk_bf16_f32 %0, %1, %2" : "=v"(phi) : "v"(sA[jj][2]), "v"(sA[jj][3]));
                uint2 pv; pv.x = plo; pv.y = phi;
                *(uint2*)&Ps[w][lr][j * 16 + lg * 4] = pv;
                asm("v_cvt_pk_bf16_f32 %0, %1, %2" : "=v"(plo) : "v"(sB[jj][0]), "v"(sB[jj][1]));
                asm("v_cvt_pk_bf16_f32 %0, %1, %2" : "=v"(phi) : "v"(sB[jj][2]), "v"(sB[jj][3]));
                pv.x = plo; pv.y = phi;
                *(uint2*)&Ps[w][16 + lr][j * 16 + lg * 4] = pv;
            }

            __builtin_amdgcn_s_setprio(1);
            #pragma unroll
            for (int ks2 = 0; ks2 < 2; ++ks2) {
                const int cb = (hp * 128 + ks2 * 64 + colb) ^ xorp;
                bf16x8 pfA = *(const bf16x8*)&Ps[w][lr][ks2 * 32 + lg * 8];
                bf16x8 pfB = *(const bf16x8*)&Ps[w][16 + lr][ks2 * 32 + lg * 8];
                #pragma unroll
                for (int m = 0; m < 4; ++m) {
                    bf16x8 vf = *(const bf16x8*)(lv + (((m * 16 + lr) << 8) + cb));
                    oA[m] = __builtin_amdgcn_mfma_f32_16x16x32_bf16(vf, pfA, oA[m], 0, 0, 0);
                    oB[m] = __builtin_amdgcn_mfma_f32_16x16x32_bf16(vf, pfB, oB[m], 0, 0, 0);
                }
            }
            __builtin_amdgcn_s_setprio(0);
        }
        __builtin_amdgcn_s_barrier();                 // all waves done with buf c
        __builtin_amdgcn_sched_barrier(0);
        c ^= 1;
    }

    // denominators (once), normalize, write merged-head T (bf16)
    lsA += __shfl_xor(lsA, 16); lsA += __shfl_xor(lsA, 32);
    lsB += __shfl_xor(lsB, 16); lsB += __shfl_xor(lsB, 32);
    const float invA = 1.f / lsA, invB = 1.f / lsB;
    const size_t trA = ((size_t)ns * LQ + row0 + w * 32 + lr) * DM + h * DHD;
    const size_t trB = trA + (size_t)16 * DM;
    #pragma unroll
    for (int m = 0; m < 4; ++m) {
        union { u16 u[4]; uint2 v; } pk;
        pk.u[0] = f2bf(oA[m][0] * invA); pk.u[1] = f2bf(oA[m][1] * invA);
        pk.u[2] = f2bf(oA[m][2] * invA); pk.u[3] = f2bf(oA[m][3] * invA);
        *(uint2*)&Tbf[trA + m * 16 + lg * 4] = pk.v;
        pk.u[0] = f2bf(oB[m][0] * invB); pk.u[1] = f2bf(oB[m][1] * invB);
        pk.u[2] = f2bf(oB[m][2] * invB); pk.u[3] = f2bf(oB[m][3] * invB);
        *(uint2*)&Tbf[trB + m * 16 + lg * 4] = pk.v;
    }
}

// ---------------------------------------------------------------------------
// BN: reduce per-block partials (64 m-blocks) -> stats; then final
// (Y is bf16; f32 stats; float4-wide output)
// ---------------------------------------------------------------------------
__global__ __launch_bounds__(256)
void bn_reduce(const float* __restrict__ part, float* __restrict__ stats)
{
    const int cx = blockIdx.x * 256 + threadIdx.x;   // 0..511
    float s = 0.f, s2 = 0.f;
    for (int b = 0; b < 64; ++b) {
        s  += part[(size_t)b * 512 + cx];
        s2 += part[32768 + (size_t)b * 512 + cx];
    }
    stats[cx] = s;
    stats[512 + cx] = s2;
}

__global__ __launch_bounds__(256)
void bn_final(const u16* __restrict__ Y, const float* __restrict__ Qin,
              const float* __restrict__ stats,
              const float* __restrict__ gamma, const float* __restrict__ beta,
              float* __restrict__ out)
{
    const int i4 = blockIdx.x * 256 + threadIdx.x;   // 0..ROWS*DM/4-1
    const int c4 = (i4 & 127) * 4;                   // channel base
    const float4 sm  = *(const float4*)&stats[c4];
    const float4 sq  = *(const float4*)&stats[512 + c4];
    const float4 gm  = *(const float4*)&gamma[c4];
    const float4 bt  = *(const float4*)&beta[c4];
    union { u16 u[4]; uint2 v; } yv;
    yv.v = *(const uint2*)&Y[(size_t)i4 * 4];
    const float4 q   = *(const float4*)&Qin[(size_t)i4 * 4];
    float4 o;
    {
        const float mu = sm.x * (1.f / ROWS);
        const float rs = rsqrtf(sq.x * (1.f / ROWS) - mu * mu + 1e-5f);
        o.x = q.x + (bf2f(yv.u[0]) - mu) * rs * gm.x + bt.x;
    }
    {
        const float mu = sm.y * (1.f / ROWS);
        const float rs = rsqrtf(sq.y * (1.f / ROWS) - mu * mu + 1e-5f);
        o.y = q.y + (bf2f(yv.u[1]) - mu) * rs * gm.y + bt.y;
    }
    {
        const float mu = sm.z * (1.f / ROWS);
        const float rs = rsqrtf(sq.z * (1.f / ROWS) - mu * mu + 1e-5f);
        o.z = q.z + (bf2f(yv.u[2]) - mu) * rs * gm.z + bt.z;
    }
    {
        const float mu = sm.w * (1.f / ROWS);
        const float rs = rsqrtf(sq.w * (1.f / ROWS) - mu * mu + 1e-5f);
        o.w = q.w + (bf2f(yv.u[3]) - mu) * rs * gm.w + bt.w;
    }
    *(float4*)&out[(size_t)i4 * 4] = o;
}

// ---------------------------------------------------------------------------
extern "C" void kernel_launch(void* const* d_in, const int* in_sizes, int n_in,
                              void* d_out, int out_size, void* d_ws, size_t ws_size,
                              hipStream_t stream)
{
    (void)in_sizes; (void)n_in; (void)out_size; (void)ws_size;

    const float* Q    = (const float*)d_in[0];
    const float* K    = (const float*)d_in[1];
    const float* Pq   = (const float*)d_in[2];
    const float* Pk   = (const float*)d_in[3];
    const float* Wq   = (const float*)d_in[4];
    const float* bq   = (const float*)d_in[5];
    const float* Wk   = (const float*)d_in[6];
    const float* bk   = (const float*)d_in[7];
    const float* Wv   = (const float*)d_in[8];
    const float* bv   = (const float*)d_in[9];
    const float* Wp   = (const float*)d_in[10];
    const float* bp   = (const float*)d_in[11];
    const float* We   = (const float*)d_in[12];
    const float* be   = (const float*)d_in[13];
    const float* Wc   = (const float*)d_in[14];
    const float* bc   = (const float*)d_in[15];
    const float* gamma= (const float*)d_in[16];
    const float* beta = (const float*)d_in[17];

    const size_t MB = 1u << 20;
    char* w8 = (char*)d_ws;
    u16*  Abf  = (u16*)(w8);                  // 16 MB (A operands)
    u16*  Bbf  = (u16*)(w8 + 16 * MB);        // 16 MB
    u16*  Vtb  = (u16*)(w8 + 32 * MB);        //  8 MB
    u16*  Tbf  = (u16*)(w8 + 40 * MB);        //  8 MB
    u16*  H1b  = (u16*)(w8 + 48 * MB);        // 16 MB
    u16*  Qbf  = (u16*)(w8 + 64 * MB);        //  8 MB
    u16*  Kbf  = (u16*)(w8 + 72 * MB);        //  8 MB
    u16*  Ybf  = (u16*)(w8);                  //  8 MB (reuses Abf after attn)
    float* part  = (float*)(w8 + 16 * MB);    // 256 KB (reuses Bbf after attn)
    float* stats = (float*)(w8 + 17 * MB);    //  4 KB
    u16*  Wqb  = (u16*)(w8 + 80 * MB);                    // 0.5 MB
    u16*  Wkvb = (u16*)(w8 + 80 * MB + 512 * 1024);       // 1 MB
    u16*  Web  = (u16*)(w8 + 80 * MB + 1536 * 1024);      // 1 MB
    u16*  Wcb  = (u16*)(w8 + 80 * MB + 2560 * 1024);      // 1 MB

    dim3 blk256(256);

    // one fused cast: weights + Q + K
    castall<<<4992, blk256, 0, stream>>>(Wq, Wk, Wv, We, Wc, Q, K,
                                         Wqb, Wkvb, Web, Wcb, Qbf, Kbf);

    // fused Q-proj + KV-proj (one dispatch, 768 blocks, pure gload_lds path)
    proj_qkv<<<dim3(64, 12), blk256, 0, stream>>>(Qbf, Kbf, Wqb, Wkvb,
        bq, bk, bv, Abf, Bbf, Vtb, Pq, Pk, Wp, bp);

    // flash attention (256 blocks x 8 waves, KVBLK=128, 1 block/CU)
    attn_mfma<<<256, dim3(512), 0, stream>>>(Abf, Bbf, Vtb, Tbf);

    // FFN (Y emitted as bf16 + f32 BN partials)
    gemm_k<1><<<dim3(64, 8), blk256, 0, stream>>>(Tbf, Web, be, H1b, DM, 2 * DM, nullptr);
    gemm_k<0><<<dim3(64, 4), blk256, 0, stream>>>(H1b, Wcb, bc, Ybf, 2 * DM, DM, part);

    // BN stats + final
    bn_reduce<<<2, blk256, 0, stream>>>(part, stats);
    bn_final<<<ROWS * DM / 1024, blk256, 0, stream>>>(Ybf, Q, stats, gamma, beta,
                                                      (float*)d_out);
}

// Round 15
// 124.003 us; speedup vs baseline: 1.2467x; 1.1218x over previous
//
#include <hip/hip_runtime.h>
#include <math.h>

#define LQ 1024      // sequence length L
#define DM 512       // model dim D
#define HN 8         // heads
#define DHD 64       // head dim
#define ROWS 8192    // N*S*L
#define DE 128       // effective attention dim (2*DHD)
#define LOG2E 1.44269504088896f

typedef __attribute__((ext_vector_type(8))) short bf16x8;
typedef __attribute__((ext_vector_type(4))) float floatx4;
typedef unsigned short u16;

static __device__ __forceinline__ u16 f2bf(float x) {
    unsigned int u = __float_as_uint(x);
    u = (u + 0x7fffu + ((u >> 16) & 1u)) >> 16;   // round-nearest-even
    return (u16)u;
}

static __device__ __forceinline__ float bf2f(u16 u) {
    return __uint_as_float(((unsigned)u) << 16);
}

static __device__ __forceinline__ void gload16(const void* g, void* l) {
    __builtin_amdgcn_global_load_lds((const __attribute__((address_space(1))) void*)g,
                                     (__attribute__((address_space(3))) void*)l,
                                     16, 0, 0);
}

static __device__ __forceinline__ void cvt8(const float* s, u16* d, size_t o) {
    const float4* sp = (const float4*)s + 2 * o;
    float4 a = sp[0], b = sp[1];
    union { u16 u[8]; uint4 v; } ov;
    ov.u[0]=f2bf(a.x); ov.u[1]=f2bf(a.y); ov.u[2]=f2bf(a.z); ov.u[3]=f2bf(a.w);
    ov.u[4]=f2bf(b.x); ov.u[5]=f2bf(b.y); ov.u[6]=f2bf(b.z); ov.u[7]=f2bf(b.w);
    ((uint4*)d)[o] = ov.v;
}

// ---------------------------------------------------------------------------
// one fused cast dispatch: all weights + Q + K  (memory-bound)
// ---------------------------------------------------------------------------
__global__ __launch_bounds__(256)
void castall(const float* __restrict__ Wq, const float* __restrict__ Wk,
             const float* __restrict__ Wv, const float* __restrict__ We,
             const float* __restrict__ Wc, const float* __restrict__ Q,
             const float* __restrict__ K,
             u16* __restrict__ Wqb, u16* __restrict__ Wkvb,
             u16* __restrict__ Web, u16* __restrict__ Wcb,
             u16* __restrict__ Qb, u16* __restrict__ Kb)
{
    int i = blockIdx.x * 256 + threadIdx.x;      // vec8 id, total 1277952
    const float* s; u16* d; int o;
    if (i < 32768)        { s = Wq; d = Wqb;            o = i; }
    else if (i < 65536)   { s = Wk; d = Wkvb;           o = i - 32768; }
    else if (i < 98304)   { s = Wv; d = Wkvb + 262144;  o = i - 65536; }
    else if (i < 163840)  { s = We; d = Web;            o = i - 98304; }
    else if (i < 229376)  { s = Wc; d = Wcb;            o = i - 163840; }
    else if (i < 753664)  { s = Q;  d = Qb;             o = i - 229376; }
    else                  { s = K;  d = Kb;             o = i - 753664; }
    cvt8(s, d, (size_t)o);
}

// ---------------------------------------------------------------------------
// Fused projection GEMM: one dispatch, grid (64, 12).
// blockIdx.y < 4 : Q-proj -> A      blockIdx.y >= 4: KV-proj -> B / Vt
// 128x128 tile, BK=64, counted-vmcnt dual-barrier 2-phase dbuf.
// Epilogues restage through LDS (reusing the 64 KB staging pool) so ALL
// global writes are 16B coalesced.
// ---------------------------------------------------------------------------
__global__ __launch_bounds__(256)
void proj_qkv(const u16* __restrict__ Qb, const u16* __restrict__ Kb,
              const u16* __restrict__ Wqb, const u16* __restrict__ Wkvb,
              const float* __restrict__ bq, const float* __restrict__ bk,
              const float* __restrict__ bv,
              u16* __restrict__ Abf, u16* __restrict__ Bbf, u16* __restrict__ Vtb,
              const float* __restrict__ Pq, const float* __restrict__ Pk,
              const float* __restrict__ Wp, const float* __restrict__ bp)
{
    const bool isQ = blockIdx.y < 4;
    const int m0 = blockIdx.x * 128;
    const int n0 = (isQ ? blockIdx.y : blockIdx.y - 4) * 128;
    const u16* Xb = isQ ? Qb : Kb;
    const u16* W  = isQ ? Wqb : Wkvb;
    const float* Pph = isQ ? Pq : Pk;
    const int Kd = DM;

    const int tid = threadIdx.x;
    const int w = tid >> 6, lane = tid & 63;
    const int lr = lane & 15, lg = lane >> 4;
    const int wm = w >> 1, wn = w & 1;

    // 64 KB pool: staging (AsL/BsL dbuf) during loop, transpose buf in epilogue
    __shared__ __align__(16) u16 pool[32768];

    floatx4 acc[4][4] = {};
    const int xorp = (lr & 7) << 4;
    const int colb = lg << 4;

    auto stage = [&](int t, int b) {
        const size_t ko = (size_t)t * 64;
        #pragma unroll
        for (int r = 0; r < 4; ++r) {
            const int cid = r * 256 + tid;
            const int row = cid >> 3, c16 = cid & 7;
            const int kc = ((c16 ^ (row & 7)) << 3);
            gload16(&Xb[(size_t)(m0 + row) * Kd + ko + kc], &pool[b * 8192 + cid * 8]);
        }
        #pragma unroll
        for (int r = 0; r < 4; ++r) {
            const int cid = r * 256 + tid;
            const int row = cid >> 3, c16 = cid & 7;
            const int kc = ((c16 ^ (row & 7)) << 3);
            gload16(&W[(size_t)(n0 + row) * Kd + ko + kc], &pool[16384 + b * 8192 + cid * 8]);
        }
    };

    const int nt = Kd >> 6;
    stage(0, 0);
    int c = 0;
    for (int t = 0; t < nt; ++t) {
        if (t + 1 < nt) {
            stage(t + 1, c ^ 1);                       // 8 loads stay in flight
            asm volatile("s_waitcnt vmcnt(8)" ::: "memory");
        } else {
            asm volatile("s_waitcnt vmcnt(0)" ::: "memory");
        }
        __builtin_amdgcn_sched_barrier(0);
        __builtin_amdgcn_s_barrier();                  // buf c staged for all waves

        const char* la = (const char*)(pool + c * 8192);
        const char* lb = (const char*)(pool + 16384 + c * 8192);
        __builtin_amdgcn_s_setprio(1);
        #pragma unroll
        for (int ks = 0; ks < 2; ++ks) {
            const int cb = (ks * 64 + colb) ^ xorp;
            bf16x8 a[4], b[4];
            #pragma unroll
            for (int i = 0; i < 4; ++i)
                a[i] = *(const bf16x8*)(la + (((wm * 64 + i * 16 + lr) << 7) + cb));
            #pragma unroll
            for (int j = 0; j < 4; ++j)
                b[j] = *(const bf16x8*)(lb + (((wn * 64 + j * 16 + lr) << 7) + cb));
            #pragma unroll
            for (int i = 0; i < 4; ++i)
                #pragma unroll
                for (int j = 0; j < 4; ++j)
                    acc[i][j] = __builtin_amdgcn_mfma_f32_16x16x32_bf16(a[i], b[j], acc[i][j], 0, 0, 0);
        }
        __builtin_amdgcn_s_setprio(0);
        __builtin_amdgcn_s_barrier();                  // all waves done reading buf c
        __builtin_amdgcn_sched_barrier(0);
        c ^= 1;
    }
    __syncthreads();       // staging pool now free for epilogue reuse

    const int ns = m0 >> 10;            // constant within block (128 | 1024)
    const int lbase = m0 & 1023;

    if (isQ || n0 < 512) {
        // ---- A or B: stage [lh][l][128] (granule-XOR by l&7), write 16B runs
        const float* bias = isQ ? bq : bk;
        #pragma unroll
        for (int j = 0; j < 4; ++j) {
            const int col = n0 + wn * 64 + j * 16 + lr;
            const float w0 = Wp[col * 3], w1 = Wp[col * 3 + 1], w2 = Wp[col * 3 + 2];
            const float bpd = isQ ? bp[col] : 0.f;
            const float bi = bias[col];
            const int lh = (col - n0) >> 6, dh = col & 63;
            #pragma unroll
            for (int i = 0; i < 4; ++i)
                #pragma unroll
                for (int rr = 0; rr < 4; ++rr) {
                    const int l = wm * 64 + i * 16 + lg * 4 + rr;
                    const int row = m0 + l;
                    const float p = Pph[row * 3] * w0 + Pph[row * 3 + 1] * w1
                                  + Pph[row * 3 + 2] * w2 + bpd;
                    float sn, cs;
                    __sincosf(p, &sn, &cs);
                    const float v = acc[i][j][rr] + bi;
                    const int base = (lh * 128 + l) * 128;
                    const int g1 = (dh >> 3) ^ (l & 7);
                    const int g2 = (8 + (dh >> 3)) ^ (l & 7);
                    if (isQ) {
                        pool[base + g1 * 8 + (dh & 7)] = f2bf(v * sn * LOG2E);
                        pool[base + g2 * 8 + (dh & 7)] = f2bf(-v * cs * LOG2E);
                    } else {
                        pool[base + g1 * 8 + (dh & 7)] = f2bf(v * cs);
                        pool[base + g2 * 8 + (dh & 7)] = f2bf(v * sn);
                    }
                }
        }
        __syncthreads();
        u16* dst = isQ ? Abf : Bbf;
        const int hhb = n0 >> 6;
        #pragma unroll
        for (int k = 0; k < 16; ++k) {
            const int idx = k * 256 + tid;            // 4096 granules
            const int lh = idx >> 11, l = (idx >> 4) & 127, g = idx & 15;
            const int gp = g ^ (l & 7);
            uint4 val = *(const uint4*)&pool[(lh * 128 + l) * 128 + gp * 8];
            const size_t e = (((size_t)(ns * HN + hhb + lh)) * LQ + lbase + l) * DE + g * 8;
            *(uint4*)&dst[e] = val;
        }
    } else {
        // ---- Vt: stage transposed [c][l] (granule-XOR by c&15), write runs
        #pragma unroll
        for (int j = 0; j < 4; ++j) {
            const int col = n0 + wn * 64 + j * 16 + lr;
            const int cc = col - n0;                  // 0..127
            const float bi = bv[(col - 512) & 511];   // c2 = col-512 (n0>=512)
            #pragma unroll
            for (int i = 0; i < 4; ++i)
                #pragma unroll
                for (int rr = 0; rr < 4; ++rr) {
                    const int l = wm * 64 + i * 16 + lg * 4 + rr;
                    const float v = acc[i][j][rr] + bi;
                    const int glp = (l >> 3) ^ (cc & 15);
                    pool[cc * 128 + glp * 8 + (l & 7)] = f2bf(v);
                }
        }
        __syncthreads();
        const int c2b = n0 - 512;
        #pragma unroll
        for (int k = 0; k < 8; ++k) {
            const int idx = k * 256 + tid;            // 2048 granules
            const int cc = idx >> 4, g = idx & 15;
            const int glp = g ^ (cc & 15);
            uint4 val = *(const uint4*)&pool[cc * 128 + glp * 8];
            const int c2 = c2b + cc;
            const int hh = c2 >> 6, dh = c2 & 63;
            const size_t e = ((size_t)((ns * HN + hh) * DHD + dh)) * LQ + lbase + g * 8;
            *(uint4*)&Vtb[e] = val;
        }
    }
}

// ---------------------------------------------------------------------------
// FFN GEMM: 128x128, BK=64, counted-vmcnt dual-barrier 2-phase dbuf.
// MODE 0: bf16 out + bias + BN partials (f32 sums)   MODE 1: bf16 out + relu
// ---------------------------------------------------------------------------
template<int MODE>
__global__ __launch_bounds__(256)
void gemm_k(const u16* __restrict__ Xb, const u16* __restrict__ W,
            const float* __restrict__ bias, void* __restrict__ out,
            int Kd, int Nn, float* __restrict__ bnp)
{
    const int m0 = blockIdx.x * 128, n0 = blockIdx.y * 128;
    const int tid = threadIdx.x;
    const int w = tid >> 6, lane = tid & 63;
    const int lr = lane & 15, lg = lane >> 4;
    const int wm = w >> 1, wn = w & 1;

    __shared__ __align__(16) u16 AsL[2][128 * 64];
    __shared__ __align__(16) u16 BsL[2][128 * 64];
    __shared__ float BnL[2][2][4][16][2];

    floatx4 acc[4][4] = {};
    const int xorp = (lr & 7) << 4;
    const int colb = lg << 4;

    auto stage = [&](int t, int b) {
        const size_t ko = (size_t)t * 64;
        #pragma unroll
        for (int r = 0; r < 4; ++r) {
            const int cid = r * 256 + tid;
            const int row = cid >> 3, c16 = cid & 7;
            const int kc = ((c16 ^ (row & 7)) << 3);
            gload16(&Xb[(size_t)(m0 + row) * Kd + ko + kc], &AsL[b][cid * 8]);
        }
        #pragma unroll
        for (int r = 0; r < 4; ++r) {
            const int cid = r * 256 + tid;
            const int row = cid >> 3, c16 = cid & 7;
            const int kc = ((c16 ^ (row & 7)) << 3);
            gload16(&W[(size_t)(n0 + row) * Kd + ko + kc], &BsL[b][cid * 8]);
        }
    };

    const int nt = Kd >> 6;
    stage(0, 0);
    int c = 0;
    for (int t = 0; t < nt; ++t) {
        if (t + 1 < nt) {
            stage(t + 1, c ^ 1);                       // 8 loads stay in flight
            asm volatile("s_waitcnt vmcnt(8)" ::: "memory");
        } else {
            asm volatile("s_waitcnt vmcnt(0)" ::: "memory");
        }
        __builtin_amdgcn_sched_barrier(0);
        __builtin_amdgcn_s_barrier();                  // buf c staged for all waves

        const char* la = (const char*)AsL[c];
        const char* lb = (const char*)BsL[c];
        __builtin_amdgcn_s_setprio(1);
        #pragma unroll
        for (int ks = 0; ks < 2; ++ks) {
            const int cb = (ks * 64 + colb) ^ xorp;
            bf16x8 a[4], b[4];
            #pragma unroll
            for (int i = 0; i < 4; ++i)
                a[i] = *(const bf16x8*)(la + (((wm * 64 + i * 16 + lr) << 7) + cb));
            #pragma unroll
            for (int j = 0; j < 4; ++j)
                b[j] = *(const bf16x8*)(lb + (((wn * 64 + j * 16 + lr) << 7) + cb));
            #pragma unroll
            for (int i = 0; i < 4; ++i)
                #pragma unroll
                for (int j = 0; j < 4; ++j)
                    acc[i][j] = __builtin_amdgcn_mfma_f32_16x16x32_bf16(a[i], b[j], acc[i][j], 0, 0, 0);
        }
        __builtin_amdgcn_s_setprio(0);
        __builtin_amdgcn_s_barrier();                  // all waves done reading buf c
        __builtin_amdgcn_sched_barrier(0);
        c ^= 1;
    }

    float bs[4], bs2[4];
    #pragma unroll
    for (int j = 0; j < 4; ++j) { bs[j] = 0.f; bs2[j] = 0.f; }
    #pragma unroll
    for (int j = 0; j < 4; ++j) {
        const int col = n0 + wn * 64 + j * 16 + lr;
        const float bi = bias[col];
        #pragma unroll
        for (int i = 0; i < 4; ++i)
            #pragma unroll
            for (int rr = 0; rr < 4; ++rr) {
                const int row = m0 + wm * 64 + i * 16 + lg * 4 + rr;
                float v = acc[i][j][rr] + bi;
                if (MODE == 1) {
                    v = fmaxf(v, 0.f);
                    ((u16*)out)[(size_t)row * Nn + col] = f2bf(v);
                } else {
                    ((u16*)out)[(size_t)row * Nn + col] = f2bf(v);
                    bs[j] += v; bs2[j] += v * v;
                }
            }
    }
    if (MODE == 0) {    // BN partial over this m-tile's 128 rows
        #pragma unroll
        for (int j = 0; j < 4; ++j) {
            float s = bs[j], s2 = bs2[j];
            s  += __shfl_xor(s, 16);  s  += __shfl_xor(s, 32);
            s2 += __shfl_xor(s2, 16); s2 += __shfl_xor(s2, 32);
            if (lg == 0) { BnL[wm][wn][j][lr][0] = s; BnL[wm][wn][j][lr][1] = s2; }
        }
        __syncthreads();
        if (tid < 128) {
            const int wn2 = tid >> 6, j2 = (tid >> 4) & 3, lr2 = tid & 15;
            const float s  = BnL[0][wn2][j2][lr2][0] + BnL[1][wn2][j2][lr2][0];
            const float s2 = BnL[0][wn2][j2][lr2][1] + BnL[1][wn2][j2][lr2][1];
            const int col = n0 + tid;
            bnp[(size_t)blockIdx.x * 512 + col]         = s;
            bnp[32768 + (size_t)blockIdx.x * 512 + col] = s2;
        }
    }
}

// ---------------------------------------------------------------------------
// Flash attention (R14): 512-thr blocks (8 waves), QBLK=256, KVBLK=128.
// Dual 16-q groups per wave; PV as two 64-key half-passes; counted-vmcnt.
// ---------------------------------------------------------------------------
__global__ __launch_bounds__(512, 2)
void attn_mfma(const u16* __restrict__ Ag, const u16* __restrict__ Bg,
               const u16* __restrict__ Vtg, u16* __restrict__ Tbf)
{
    int bid = blockIdx.x;
    bid = (bid & 7) * 32 + (bid >> 3);    // XCD swizzle (256 % 8 == 0): 8 heads/XCD
    const int head = bid >> 2;            // 0..63
    const int row0 = (bid & 3) * 256;
    const int ns = head >> 3, h = head & 7;
    const int tid = threadIdx.x, w = tid >> 6, lane = tid & 63;
    const int lr = lane & 15, lg = lane >> 4;

    __shared__ __align__(16) u16 BsL[2][128 * 128];  // 64 KB
    __shared__ __align__(16) u16 VtL[2][64 * 128];   // 32 KB
    __shared__ __align__(16) u16 Ps[8][32][72];      // 36 KB

    bf16x8 qfA[4], qfB[4];
    {
        const size_t rb = ((size_t)head * LQ + row0 + w * 32 + lr) * DE;
        #pragma unroll
        for (int ks = 0; ks < 4; ++ks) {
            qfA[ks] = *(const bf16x8*)&Ag[rb + ks * 32 + lg * 8];
            qfB[ks] = *(const bf16x8*)&Ag[rb + 16 * DE + ks * 32 + lg * 8];
        }
    }

    auto stageKV = [&](int kt, int b) {
        #pragma unroll
        for (int r = 0; r < 4; ++r) {
            const int cid = r * 512 + tid;
            const int row = cid >> 4, c16 = cid & 15;
            const int kc = ((c16 ^ (row & 7)) << 3);
            gload16(&Bg[((size_t)head * LQ + kt * 128 + row) * DE + kc], &BsL[b][cid * 8]);
        }
        #pragma unroll
        for (int r = 0; r < 2; ++r) {
            const int cid = r * 512 + tid;
            const int row = cid >> 4, c16 = cid & 15;
            const int kc = ((c16 ^ (row & 7)) << 3);
            gload16(&Vtg[((size_t)head * DHD + row) * LQ + kt * 128 + kc], &VtL[b][cid * 8]);
        }
    };
    stageKV(0, 0);

    floatx4 oA[4] = {}, oB[4] = {};
    float lsA = 0.f, lsB = 0.f;
    const int xorp = (lr & 7) << 4;
    const int colb = lg << 4;
    int c = 0;

    for (int kt = 0; kt < 8; ++kt) {
        if (kt < 7) {
            stageKV(kt + 1, c ^ 1);
            asm volatile("s_waitcnt vmcnt(6)" ::: "memory");
        } else {
            asm volatile("s_waitcnt vmcnt(0)" ::: "memory");
        }
        __builtin_amdgcn_sched_barrier(0);
        __builtin_amdgcn_s_barrier();

        const char* lb = (const char*)BsL[c];
        const char* lv = (const char*)VtL[c];

        floatx4 sA[8] = {}, sB[8] = {};
        __builtin_amdgcn_s_setprio(1);
        #pragma unroll
        for (int ks = 0; ks < 4; ++ks) {
            const int cb = (ks * 64 + colb) ^ xorp;
            #pragma unroll
            for (int j = 0; j < 8; ++j) {
                bf16x8 kf = *(const bf16x8*)(lb + (((j * 16 + lr) << 8) + cb));
                sA[j] = __builtin_amdgcn_mfma_f32_16x16x32_bf16(kf, qfA[ks], sA[j], 0, 0, 0);
                sB[j] = __builtin_amdgcn_mfma_f32_16x16x32_bf16(kf, qfB[ks], sB[j], 0, 0, 0);
            }
        }
        __builtin_amdgcn_s_setprio(0);

        float tsa = 0.f, tsb = 0.f;
        #pragma unroll
        for (int j = 0; j < 8; ++j)
            #pragma unroll
            for (int r = 0; r < 4; ++r) {
                float ea = exp2f(sA[j][r]); sA[j][r] = ea; tsa += ea;
                float eb = exp2f(sB[j][r]); sB[j][r] = eb; tsb += eb;
            }
        lsA += tsa; lsB += tsb;

        #pragma unroll
        for (int hp = 0; hp < 2; ++hp) {
            #pragma unroll
            for (int j = 0; j < 4; ++j) {
                const int jj = hp * 4 + j;
                unsigned plo, phi;
                asm("v_cvt_pk_bf16_f32 %0, %1, %2" : "=v"(plo) : "v"(sA[jj][0]), "v"(sA[jj][1]));
                asm("v_cvt_pk_bf16_f32 %0, %1, %2" : "=v"(phi) : "v"(sA[jj][2]), "v"(sA[jj][3]));
                uint2 pv; pv.x = plo; pv.y = phi;
                *(uint2*)&Ps[w][lr][j * 16 + lg * 4] = pv;
                asm("v_cvt_pk_bf16_f32 %0, %1, %2" : "=v"(plo) : "v"(sB[jj][0]), "v"(sB[jj][1]));
                asm("v_cvt_pk_bf16_f32 %0, %1, %2" : "=v"(phi) : "v"(sB[jj][2]), "v"(sB[jj][3]));
                pv.x = plo; pv.y = phi;
                *(uint2*)&Ps[w][16 + lr][j * 16 + lg * 4] = pv;
            }

            __builtin_amdgcn_s_setprio(1);
            #pragma unroll
            for (int ks2 = 0; ks2 < 2; ++ks2) {
                const int cb = (hp * 128 + ks2 * 64 + colb) ^ xorp;
                bf16x8 pfA = *(const bf16x8*)&Ps[w][lr][ks2 * 32 + lg * 8];
                bf16x8 pfB = *(const bf16x8*)&Ps[w][16 + lr][ks2 * 32 + lg * 8];
                #pragma unroll
                for (int m = 0; m < 4; ++m) {
                    bf16x8 vf = *(const bf16x8*)(lv + (((m * 16 + lr) << 8) + cb));
                    oA[m] = __builtin_amdgcn_mfma_f32_16x16x32_bf16(vf, pfA, oA[m], 0, 0, 0);
                    oB[m] = __builtin_amdgcn_mfma_f32_16x16x32_bf16(vf, pfB, oB[m], 0, 0, 0);
                }
            }
            __builtin_amdgcn_s_setprio(0);
        }
        __builtin_amdgcn_s_barrier();
        __builtin_amdgcn_sched_barrier(0);
        c ^= 1;
    }

    lsA += __shfl_xor(lsA, 16); lsA += __shfl_xor(lsA, 32);
    lsB += __shfl_xor(lsB, 16); lsB += __shfl_xor(lsB, 32);
    const float invA = 1.f / lsA, invB = 1.f / lsB;
    const size_t trA = ((size_t)ns * LQ + row0 + w * 32 + lr) * DM + h * DHD;
    const size_t trB = trA + (size_t)16 * DM;
    #pragma unroll
    for (int m = 0; m < 4; ++m) {
        union { u16 u[4]; uint2 v; } pk;
        pk.u[0] = f2bf(oA[m][0] * invA); pk.u[1] = f2bf(oA[m][1] * invA);
        pk.u[2] = f2bf(oA[m][2] * invA); pk.u[3] = f2bf(oA[m][3] * invA);
        *(uint2*)&Tbf[trA + m * 16 + lg * 4] = pk.v;
        pk.u[0] = f2bf(oB[m][0] * invB); pk.u[1] = f2bf(oB[m][1] * invB);
        pk.u[2] = f2bf(oB[m][2] * invB); pk.u[3] = f2bf(oB[m][3] * invB);
        *(uint2*)&Tbf[trB + m * 16 + lg * 4] = pk.v;
    }
}

// ---------------------------------------------------------------------------
// BN: reduce per-block partials (64 m-blocks) -> stats; then final
// ---------------------------------------------------------------------------
__global__ __launch_bounds__(256)
void bn_reduce(const float* __restrict__ part, float* __restrict__ stats)
{
    const int cx = blockIdx.x * 256 + threadIdx.x;   // 0..511
    float s = 0.f, s2 = 0.f;
    for (int b = 0; b < 64; ++b) {
        s  += part[(size_t)b * 512 + cx];
        s2 += part[32768 + (size_t)b * 512 + cx];
    }
    stats[cx] = s;
    stats[512 + cx] = s2;
}

__global__ __launch_bounds__(256)
void bn_final(const u16* __restrict__ Y, const float* __restrict__ Qin,
              const float* __restrict__ stats,
              const float* __restrict__ gamma, const float* __restrict__ beta,
              float* __restrict__ out)
{
    const int i4 = blockIdx.x * 256 + threadIdx.x;   // 0..ROWS*DM/4-1
    const int c4 = (i4 & 127) * 4;                   // channel base
    const float4 sm  = *(const float4*)&stats[c4];
    const float4 sq  = *(const float4*)&stats[512 + c4];
    const float4 gm  = *(const float4*)&gamma[c4];
    const float4 bt  = *(const float4*)&beta[c4];
    union { u16 u[4]; uint2 v; } yv;
    yv.v = *(const uint2*)&Y[(size_t)i4 * 4];
    const float4 q   = *(const float4*)&Qin[(size_t)i4 * 4];
    float4 o;
    {
        const float mu = sm.x * (1.f / ROWS);
        const float rs = rsqrtf(sq.x * (1.f / ROWS) - mu * mu + 1e-5f);
        o.x = q.x + (bf2f(yv.u[0]) - mu) * rs * gm.x + bt.x;
    }
    {
        const float mu = sm.y * (1.f / ROWS);
        const float rs = rsqrtf(sq.y * (1.f / ROWS) - mu * mu + 1e-5f);
        o.y = q.y + (bf2f(yv.u[1]) - mu) * rs * gm.y + bt.y;
    }
    {
        const float mu = sm.z * (1.f / ROWS);
        const float rs = rsqrtf(sq.z * (1.f / ROWS) - mu * mu + 1e-5f);
        o.z = q.z + (bf2f(yv.u[2]) - mu) * rs * gm.z + bt.z;
    }
    {
        const float mu = sm.w * (1.f / ROWS);
        const float rs = rsqrtf(sq.w * (1.f / ROWS) - mu * mu + 1e-5f);
        o.w = q.w + (bf2f(yv.u[3]) - mu) * rs * gm.w + bt.w;
    }
    *(float4*)&out[(size_t)i4 * 4] = o;
}

// ---------------------------------------------------------------------------
extern "C" void kernel_launch(void* const* d_in, const int* in_sizes, int n_in,
                              void* d_out, int out_size, void* d_ws, size_t ws_size,
                              hipStream_t stream)
{
    (void)in_sizes; (void)n_in; (void)out_size; (void)ws_size;

    const float* Q    = (const float*)d_in[0];
    const float* K    = (const float*)d_in[1];
    const float* Pq   = (const float*)d_in[2];
    const float* Pk   = (const float*)d_in[3];
    const float* Wq   = (const float*)d_in[4];
    const float* bq   = (const float*)d_in[5];
    const float* Wk   = (const float*)d_in[6];
    const float* bk   = (const float*)d_in[7];
    const float* Wv   = (const float*)d_in[8];
    const float* bv   = (const float*)d_in[9];
    const float* Wp   = (const float*)d_in[10];
    const float* bp   = (const float*)d_in[11];
    const float* We   = (const float*)d_in[12];
    const float* be   = (const float*)d_in[13];
    const float* Wc   = (const float*)d_in[14];
    const float* bc   = (const float*)d_in[15];
    const float* gamma= (const float*)d_in[16];
    const float* beta = (const float*)d_in[17];

    const size_t MB = 1u << 20;
    char* w8 = (char*)d_ws;
    u16*  Abf  = (u16*)(w8);                  // 16 MB
    u16*  Bbf  = (u16*)(w8 + 16 * MB);        // 16 MB
    u16*  Vtb  = (u16*)(w8 + 32 * MB);        //  8 MB
    u16*  Tbf  = (u16*)(w8 + 40 * MB);        //  8 MB
    u16*  H1b  = (u16*)(w8 + 48 * MB);        // 16 MB
    u16*  Qbf  = (u16*)(w8 + 64 * MB);        //  8 MB
    u16*  Kbf  = (u16*)(w8 + 72 * MB);        //  8 MB
    u16*  Ybf  = (u16*)(w8);                  //  8 MB (reuses Abf after attn)
    float* part  = (float*)(w8 + 16 * MB);    // 256 KB (reuses Bbf after attn)
    float* stats = (float*)(w8 + 17 * MB);    //  4 KB
    u16*  Wqb  = (u16*)(w8 + 80 * MB);                    // 0.5 MB
    u16*  Wkvb = (u16*)(w8 + 80 * MB + 512 * 1024);       // 1 MB
    u16*  Web  = (u16*)(w8 + 80 * MB + 1536 * 1024);      // 1 MB
    u16*  Wcb  = (u16*)(w8 + 80 * MB + 2560 * 1024);      // 1 MB

    dim3 blk256(256);

    // one fused cast: weights + Q + K
    castall<<<4992, blk256, 0, stream>>>(Wq, Wk, Wv, We, Wc, Q, K,
                                         Wqb, Wkvb, Web, Wcb, Qbf, Kbf);

    // fused Q-proj + KV-proj (coalesced LDS-restaged epilogues)
    proj_qkv<<<dim3(64, 12), blk256, 0, stream>>>(Qbf, Kbf, Wqb, Wkvb,
        bq, bk, bv, Abf, Bbf, Vtb, Pq, Pk, Wp, bp);

    // flash attention (256 blocks x 8 waves, KVBLK=128)
    attn_mfma<<<256, dim3(512), 0, stream>>>(Abf, Bbf, Vtb, Tbf);

    // FFN (Y emitted as bf16 + f32 BN partials)
    gemm_k<1><<<dim3(64, 8), blk256, 0, stream>>>(Tbf, Web, be, H1b, DM, 2 * DM, nullptr);
    gemm_k<0><<<dim3(64, 4), blk256, 0, stream>>>(H1b, Wcb, bc, Ybf, 2 * DM, DM, part);

    // BN stats + final
    bn_reduce<<<2, blk256, 0, stream>>>(part, stats);
    bn_final<<<ROWS * DM / 1024, blk256, 0, stream>>>(Ybf, Q, stats, gamma, beta,
                                                      (float*)d_out);
}